// Round 12
// baseline (126.480 us; speedup 1.0000x reference)
//
#include <hip/hip_runtime.h>
#include <hip/hip_bf16.h>
#include <cstdint>
#include <cstddef>

constexpr int kN = 10000;   // nodes
constexpr int kE = 320000;  // edges
constexpr int kM = 4;       // modalities
constexpr int kD = 256;     // feature dim
constexpr int kP = 256;     // pro dim
constexpr float kSlope = 0.2f;
constexpr int kCap = 96;    // CSR capacity/node: deg ~ Poisson(32), 96 = +11 sigma

// hb / hrelb layout: [m][2][kN][128] bf16 -- feature dim split in halves so each
// (m,half) slice (2.56 MB) is L2-resident on its dedicated XCD (4 MB L2).

typedef __attribute__((ext_vector_type(8))) short bf16x8;
typedef __attribute__((ext_vector_type(4))) float f32x4;
typedef __attribute__((ext_vector_type(2))) float f32x2;

__device__ __forceinline__ unsigned short f2bf(float f) {
  union { float ff; unsigned int i; } v; v.ff = f;
  unsigned int x = v.i;
  unsigned int r = x + 0x7fffu + ((x >> 16) & 1u);
  return (unsigned short)(r >> 16);
}
__device__ __forceinline__ uint4 pack8(float4 a, float4 b) {
  uint4 o;
  o.x = (unsigned)f2bf(a.x) | ((unsigned)f2bf(a.y) << 16);
  o.y = (unsigned)f2bf(a.z) | ((unsigned)f2bf(a.w) << 16);
  o.z = (unsigned)f2bf(b.x) | ((unsigned)f2bf(b.y) << 16);
  o.w = (unsigned)f2bf(b.z) | ((unsigned)f2bf(b.w) << 16);
  return o;
}
__device__ __forceinline__ void gload_lds16(const void* g, void* l) {
  __builtin_amdgcn_global_load_lds((const __attribute__((address_space(1))) unsigned int*)g,
                                   (__attribute__((address_space(3))) unsigned int*)l, 16, 0, 0);
}

// ---------------- weight prep (critical-path only): Wgt + biasp + cnt ----------

__global__ __launch_bounds__(256) void weight_prep_kernel(
    const float* __restrict__ Wg, const float* __restrict__ bp,
    const float* __restrict__ cw, const float* __restrict__ cb,
    unsigned short* __restrict__ Wgt, float* __restrict__ biasp, int* __restrict__ cnt) {
  const int blk = blockIdx.x;
  if (blk >= 65) {
    int z = blk - 65;
    int t = threadIdx.x;
    if (t < 250) ((int4*)cnt)[z * 250 + t] = make_int4(0, 0, 0, 0);
    return;
  }
  if (blk == 64) {
    int p = threadIdx.x;
    float v = cb[0];
#pragma unroll
    for (int mm = 0; mm < kM; mm++) v += cw[mm] * bp[mm * kP + p];
    biasp[p] = v;
    return;
  }
  __shared__ float tile[64][65];
  const int m = blk >> 4;
  const int t2 = blk & 15;
  const int r0 = (t2 >> 2) * 64;
  const int c0 = (t2 & 3) * 64;
  const float* in = Wg + ((size_t)m << 16);
#pragma unroll
  for (int l = 0; l < 16; l++) {
    int idx = l * 256 + threadIdx.x;
    int rr = idx >> 6, cc = idx & 63;
    tile[rr][cc] = in[(size_t)(c0 + rr) * 256 + r0 + cc];
  }
  __syncthreads();
#pragma unroll
  for (int l = 0; l < 16; l++) {
    int idx = l * 256 + threadIdx.x;
    int rr = idx >> 6, cc = idx & 63;
    Wgt[((size_t)m << 16) + (size_t)(r0 + rr) * 256 + c0 + cc] = f2bf(tile[cc][rr]);
  }
}

// ---------------- GEMM 1 (MFMA + LDS, 2-phase dbuf) + CSR fill + Wqt prep -------
// blocks [0,632):    hb = bf16(x @ Wg) (half-split layout), fused s,t epilogue
// blocks [632,945):  capacity-CSR edge fill
// blocks [945,1009): Wqt transpose (consumed only by gemm_fused, rides for free)

constexpr int ASTR = 64 * 8 + 8;
constexpr int BSTR = 256 * 8 + 8;
constexpr int kAsBytes = 2 * 4 * ASTR * 2;
constexpr int kBsBytes = 2 * 4 * BSTR * 2;

__global__ __launch_bounds__(256) void gemm_h_csr_mfma(
    const float* __restrict__ x, const unsigned short* __restrict__ Wgt,
    const float* __restrict__ asrc, const float* __restrict__ adst,
    const int* __restrict__ ei, int* __restrict__ cnt, int* __restrict__ csr_src,
    const float* __restrict__ Wp, const float* __restrict__ cw,
    unsigned short* __restrict__ Wqt,
    unsigned short* __restrict__ hb, float* __restrict__ sv, float* __restrict__ tv) {
  const int blk = blockIdx.x;
  const int tid = threadIdx.x;

  __shared__ __align__(16) char smem[kAsBytes + kBsBytes];
  __shared__ float sred[256], tred[256];
  auto As = (unsigned short(*)[4 * ASTR])smem;
  auto Bs = (unsigned short(*)[4 * BSTR])(smem + kAsBytes);

  if (blk >= 945) {
    auto tile = (float(*)[65])smem;
    const int b = blk - 945;
    const int m = b >> 4;
    const int t2 = b & 15;
    const int r0 = (t2 >> 2) * 64;
    const int c0 = (t2 & 3) * 64;
    const float* in = Wp + ((size_t)m << 16);
    const float scale = cw[m];
#pragma unroll
    for (int l = 0; l < 16; l++) {
      int idx = l * 256 + tid;
      int rr = idx >> 6, cc = idx & 63;
      tile[rr][cc] = in[(size_t)(c0 + rr) * 256 + r0 + cc] * scale;
    }
    __syncthreads();
#pragma unroll
    for (int l = 0; l < 16; l++) {
      int idx = l * 256 + tid;
      int rr = idx >> 6, cc = idx & 63;
      Wqt[(size_t)(r0 + rr) * 1024 + (m << 8) + c0 + cc] = f2bf(tile[cc][rr]);
    }
    return;
  }

  if (blk >= 632) {
    int t = (blk - 632) * 256 + tid;
    int e4 = t * 4;
    if (e4 >= kE) return;
    int4 s4 = *(const int4*)&ei[e4];
    int4 d4 = *(const int4*)&ei[kE + e4];
    int sl;
    sl = atomicAdd(&cnt[d4.x], 1); csr_src[d4.x * kCap + sl] = s4.x;
    sl = atomicAdd(&cnt[d4.y], 1); csr_src[d4.y * kCap + sl] = s4.y;
    sl = atomicAdd(&cnt[d4.z], 1); csr_src[d4.z * kCap + sl] = s4.z;
    sl = atomicAdd(&cnt[d4.w], 1); csr_src[d4.w * kCap + sl] = s4.w;
    return;
  }

  // m -> XCD pair {2m, 2m+1}
  const int m = (blk & 7) >> 1;
  const int i = (blk >> 3) * 2 + (blk & 1);
  if (i >= 157) return;
  const int row0 = i * 64;

  const int wave = tid >> 6, lane = tid & 63;
  const int lidx = lane & 15, lslot = lane >> 4;
  const int wcol0 = wave * 64;

  const int arow_s = tid & 63, aslot_s = tid >> 6;
  const int agr = min(row0 + arow_s, kN - 1);
  const float* Abase = x + ((size_t)m * kN + agr) * kD + aslot_s * 8;
  const unsigned short* Bbase = Wgt + (size_t)m * kD * kD;

  f32x4 acc[4][4] = {};

  {
    float4 f0 = *(const float4*)(Abase);
    float4 f1 = *(const float4*)(Abase + 4);
    *(uint4*)&As[0][aslot_s * ASTR + arow_s * 8] = pack8(f0, f1);
#pragma unroll
    for (int l = 0; l < 4; l++) {
      int c = tid + l * 256;
      int col = c & 255, slot = c >> 8;
      gload_lds16(Bbase + (size_t)col * kD + slot * 8, &Bs[0][slot * BSTR + col * 8]);
    }
  }
  __syncthreads();

  int buf = 0;
  for (int t = 0; t < 8; t++) {
    float4 f0, f1;
    const bool pf = (t < 7);
    if (pf) {
      const int k1 = (t + 1) * 32;
      f0 = *(const float4*)(Abase + k1);
      f1 = *(const float4*)(Abase + k1 + 4);
#pragma unroll
      for (int l = 0; l < 4; l++) {
        int c = tid + l * 256;
        int col = c & 255, slot = c >> 8;
        gload_lds16(Bbase + (size_t)col * kD + k1 + slot * 8,
                    &Bs[buf ^ 1][slot * BSTR + col * 8]);
      }
    }
    bf16x8 a[4], bfr[4];
#pragma unroll
    for (int i2 = 0; i2 < 4; i2++)
      a[i2] = *(const bf16x8*)&As[buf][lslot * ASTR + (i2 * 16 + lidx) * 8];
#pragma unroll
    for (int j = 0; j < 4; j++)
      bfr[j] = *(const bf16x8*)&Bs[buf][lslot * BSTR + (wcol0 + j * 16 + lidx) * 8];
#pragma unroll
    for (int i2 = 0; i2 < 4; i2++)
#pragma unroll
      for (int j = 0; j < 4; j++)
        acc[i2][j] = __builtin_amdgcn_mfma_f32_16x16x32_bf16(a[i2], bfr[j], acc[i2][j], 0, 0, 0);
    if (pf) {
      *(uint4*)&As[buf ^ 1][aslot_s * ASTR + arow_s * 8] = pack8(f0, f1);
    }
    __syncthreads();
    buf ^= 1;
  }

  // epilogue: store hb (half-split layout) + fused s,t dot products
  const int slot4 = lane >> 4;
  float av[4], dv[4];
#pragma unroll
  for (int j = 0; j < 4; j++) {
    av[j] = asrc[m * kD + wcol0 + j * 16 + lidx];
    dv[j] = adst[m * kD + wcol0 + j * 16 + lidx];
  }
#pragma unroll
  for (int i2 = 0; i2 < 4; i2++) {
#pragma unroll
    for (int reg = 0; reg < 4; reg++) {
      int grow = row0 + i2 * 16 + slot4 * 4 + reg;
      float sp = 0.f, tp = 0.f;
#pragma unroll
      for (int j = 0; j < 4; j++) {
        float hv = acc[i2][j][reg];
        sp += hv * av[j];
        tp += hv * dv[j];
        if (grow < kN) {
          int gcol = wcol0 + j * 16 + lidx;
          hb[(((size_t)(m * 2) + (gcol >> 7)) * kN + grow) * 128 + (gcol & 127)] = f2bf(hv);
        }
      }
#pragma unroll
      for (int o = 1; o < 16; o <<= 1) {
        sp += __shfl_xor(sp, o);
        tp += __shfl_xor(tp, o);
      }
      if (lidx == 0) {
        sred[wave * 64 + i2 * 16 + slot4 * 4 + reg] = sp;
        tred[wave * 64 + i2 * 16 + slot4 * 4 + reg] = tp;
      }
    }
  }
  __syncthreads();
  if (tid < 64) {
    int grow = row0 + tid;
    if (grow < kN) {
      float s = sred[tid] + sred[64 + tid] + sred[128 + tid] + sred[192 + tid];
      float t = tred[tid] + tred[64 + tid] + tred[128 + tid] + tred[192 + tid];
      sv[m * kN + grow] = s;
      tv[m * kN + grow] = t;
    }
  }
}

// ---------------- GAT softmax + aggregate (capacity CSR, half-split) -----------
// Grid 20000: block = 4 waves = 4 nodes of one (m, half); (m,half) -> XCD 2m+half
// so each XCD's gather set is a 2.56 MB half-slice (L2-resident).
// Per wave: quarter-waves (16 lanes x 16B = one edge's 128 features), 4 edges /
// 4 gathers in flight (R10 operating point: TLP over deep unroll).

__global__ __launch_bounds__(256) void gat_aggregate_kernel(
    const unsigned short* __restrict__ hb, const float* __restrict__ sv,
    const float* __restrict__ tv, const float* __restrict__ bg,
    const int* __restrict__ cnt, const int* __restrict__ csr_src,
    unsigned short* __restrict__ hrelb) {
  const int l = blockIdx.x;
  const int xcd = l & 7;
  const int m = xcd >> 1;
  const int h = xcd & 1;
  const int ngroup = l >> 3;                    // [0, 2500)
  const int n = ngroup * 4 + (threadIdx.x >> 6);
  const int lane = threadIdx.x & 63;
  const int q = lane >> 4;                      // quarter = edge slot
  const int lf = lane & 15;
  const int fb = lf * 8;                        // feature block within the 128-half

  const float tt = tv[m * kN + n];
  const int b = n * kCap;
  const int deg = cnt[n];

  float a_self = sv[m * kN + n] + tt;
  a_self = fmaxf(a_self, kSlope * a_self);
  const float e_self = __expf(a_self);

  const unsigned short* hm = hb + ((((size_t)m * 2 + h) * kN) << 7) + fb;
  f32x2 acc2[4] = {};
  {
    const float es = (q == 0) ? e_self : 0.f;   // self term once per feature
    const f32x2 es2 = {es, es};
    uint4 hx = *(const uint4*)(hm + ((size_t)n << 7));
#pragma unroll
    for (int k = 0; k < 4; k++) {
      unsigned w = ((const unsigned*)&hx)[k];
      f32x2 hv2 = {__uint_as_float(w << 16), __uint_as_float(w & 0xffff0000u)};
      acc2[k] = __builtin_elementwise_fma(hv2, es2, acc2[k]);
    }
  }
  float denom = (lane == 0) ? e_self : 0.f;

  for (int c0 = 0; c0 < deg; c0 += 64) {
    int j = c0 + lane;
    float ee = 0.f;
    int src = 0;
    if (j < deg) {
      src = csr_src[b + j];
      float a = sv[m * kN + src] + tt;
      a = fmaxf(a, kSlope * a);
      ee = __expf(a);
    }
    denom += ee;
    const int cl = min(64, deg - c0);
    for (int j2 = 0; j2 < cl; j2 += 4) {
      int ja = j2 + q;                          // quarter q takes edge j2+q
      float ep = __shfl(ee, ja);                // lanes past cl: ee=0 -> harmless
      int sp = __shfl(src, ja);
      uint4 hx = *(const uint4*)(hm + ((size_t)sp << 7));
      const f32x2 ep2 = {ep, ep};
#pragma unroll
      for (int k = 0; k < 4; k++) {
        unsigned w = ((const unsigned*)&hx)[k];
        f32x2 hv2 = {__uint_as_float(w << 16), __uint_as_float(w & 0xffff0000u)};
        acc2[k] = __builtin_elementwise_fma(hv2, ep2, acc2[k]);
      }
    }
  }
#pragma unroll
  for (int o = 32; o > 0; o >>= 1) denom += __shfl_xor(denom, o);
  const float inv = 1.f / (denom + 1e-16f);

  // merge quarters: same lf across q=0..3 holds partials of the same features
#pragma unroll
  for (int k = 0; k < 4; k++) {
    acc2[k].x += __shfl_xor(acc2[k].x, 16);
    acc2[k].y += __shfl_xor(acc2[k].y, 16);
    acc2[k].x += __shfl_xor(acc2[k].x, 32);
    acc2[k].y += __shfl_xor(acc2[k].y, 32);
  }

  if (lane < 16) {
    const float* bgp = bg + m * kD + h * 128 + fb;
    float4 b0 = *(const float4*)bgp;
    float4 b1 = *(const float4*)(bgp + 4);
    float4 o0, o1;
    o0.x = fmaxf(acc2[0].x * inv + b0.x, 0.f);
    o0.y = fmaxf(acc2[0].y * inv + b0.y, 0.f);
    o0.z = fmaxf(acc2[1].x * inv + b0.z, 0.f);
    o0.w = fmaxf(acc2[1].y * inv + b0.w, 0.f);
    o1.x = fmaxf(acc2[2].x * inv + b1.x, 0.f);
    o1.y = fmaxf(acc2[2].y * inv + b1.y, 0.f);
    o1.z = fmaxf(acc2[3].x * inv + b1.z, 0.f);
    o1.w = fmaxf(acc2[3].y * inv + b1.w, 0.f);
    *(uint4*)(hrelb + ((((size_t)m * 2 + h) * kN + n) << 7) + fb) = pack8(o0, o1);
  }
}

// ---------------- GEMM 2 (MFMA + LDS, 2-phase dbuf): out = hrelb @ Wq + biasp ---
// A reads the half-split layout: K-step (BK=64) lies within one (m,half).

constexpr int FSTR = 64 * 8 + 8;

__global__ __launch_bounds__(256) void gemm_fused_mfma(const unsigned short* __restrict__ hrelb,
                                                       const unsigned short* __restrict__ Wqt,
                                                       const float* __restrict__ biasp,
                                                       float* __restrict__ out) {
  const int l = blockIdx.x;
  const int xcd = l & 7;
  const int t0 = l >> 3;
  const int c = t0 & 3;
  const int r = (t0 >> 2) * 8 + xcd;
  if (r >= 157) return;
  const int row0 = r * 64;
  const int col0 = c * 64;

  const int tid = threadIdx.x;
  const int wave = tid >> 6, lane = tid & 63;
  const int lidx = lane & 15, lslot = lane >> 4;
  const int wr = wave >> 1, wc = wave & 1;

  __shared__ __align__(16) unsigned short As[2][8 * FSTR];
  __shared__ __align__(16) unsigned short Bs[2][8 * FSTR];

  f32x4 acc[2][2] = {};

  const int arow = min(row0 + (tid & 63), kN - 1);
  const int bcol = col0 + (tid & 63);

  auto a_src = [&](int k1, int slot) -> const unsigned short* {
    const int mm = k1 >> 8;
    const int d1 = k1 & 255;
    const int hf = d1 >> 7;
    const int dd = d1 & 127;
    return hrelb + ((((size_t)mm * 2 + hf) * kN + arow) << 7) + dd + slot * 8;
  };

#pragma unroll
  for (int ll = 0; ll < 2; ll++) {
    int slot = (tid >> 6) + ll * 4;
    gload_lds16(a_src(0, slot), &As[0][slot * FSTR + (tid & 63) * 8]);
    gload_lds16(Wqt + (size_t)bcol * 1024 + slot * 8,
                &Bs[0][slot * FSTR + (tid & 63) * 8]);
  }
  __syncthreads();

  int buf = 0;
  for (int t = 0; t < 16; t++) {
    if (t < 15) {
      const int k1 = (t + 1) * 64;
#pragma unroll
      for (int ll = 0; ll < 2; ll++) {
        int slot = (tid >> 6) + ll * 4;
        gload_lds16(a_src(k1, slot), &As[buf ^ 1][slot * FSTR + (tid & 63) * 8]);
        gload_lds16(Wqt + (size_t)bcol * 1024 + k1 + slot * 8,
                    &Bs[buf ^ 1][slot * FSTR + (tid & 63) * 8]);
      }
    }
#pragma unroll
    for (int s = 0; s < 2; s++) {
      const int ks = s * 4 + lslot;
      bf16x8 a[2], bfr[2];
#pragma unroll
      for (int i = 0; i < 2; i++)
        a[i] = *(const bf16x8*)&As[buf][ks * FSTR + (wr * 32 + i * 16 + lidx) * 8];
#pragma unroll
      for (int j = 0; j < 2; j++)
        bfr[j] = *(const bf16x8*)&Bs[buf][ks * FSTR + (wc * 32 + j * 16 + lidx) * 8];
#pragma unroll
      for (int i = 0; i < 2; i++)
#pragma unroll
        for (int j = 0; j < 2; j++)
          acc[i][j] = __builtin_amdgcn_mfma_f32_16x16x32_bf16(a[i], bfr[j], acc[i][j], 0, 0, 0);
    }
    __syncthreads();
    buf ^= 1;
  }

  const int slot4 = lane >> 4;
#pragma unroll
  for (int i = 0; i < 2; i++) {
#pragma unroll
    for (int reg = 0; reg < 4; reg++) {
      int grow = row0 + wr * 32 + i * 16 + slot4 * 4 + reg;
      if (grow < kN) {
#pragma unroll
        for (int j = 0; j < 2; j++) {
          int gcol = col0 + wc * 32 + j * 16 + lidx;
          out[(size_t)grow * kP + gcol] = acc[i][j][reg] + biasp[gcol];
        }
      }
    }
  }
}

// ---------------- host launch ----------------

extern "C" void kernel_launch(void* const* d_in, const int* in_sizes, int n_in,
                              void* d_out, int out_size, void* d_ws, size_t ws_size,
                              hipStream_t stream) {
  const float* x = (const float*)d_in[0];
  const int* ei = (const int*)d_in[1];
  const float* Wg = (const float*)d_in[2];
  const float* asrc = (const float*)d_in[3];
  const float* adst = (const float*)d_in[4];
  const float* bg = (const float*)d_in[5];
  const float* Wp = (const float*)d_in[6];
  const float* bp = (const float*)d_in[7];
  const float* cw = (const float*)d_in[8];
  const float* cb = (const float*)d_in[9];
  float* out = (float*)d_out;

  char* ws = (char*)d_ws;
  size_t off = 0;
  auto alloc = [&](size_t bytes) -> void* {
    void* p = ws + off;
    off = (off + bytes + 255) & ~(size_t)255;
    return p;
  };
  unsigned short* hb = (unsigned short*)alloc((size_t)kM * kN * kD * 2);
  unsigned short* hrelb = (unsigned short*)alloc((size_t)kM * kN * kD * 2);
  unsigned short* Wgt = (unsigned short*)alloc((size_t)kM * kD * kD * 2);
  unsigned short* Wqt = (unsigned short*)alloc((size_t)kP * kM * kD * 2);
  float* sv = (float*)alloc((size_t)kM * kN * sizeof(float));
  float* tv = (float*)alloc((size_t)kM * kN * sizeof(float));
  float* biasp = (float*)alloc(kP * sizeof(float));
  int* cnt = (int*)alloc(kN * sizeof(int));
  int* csr_src = (int*)alloc((size_t)kN * kCap * sizeof(int));

  weight_prep_kernel<<<75, 256, 0, stream>>>(Wg, bp, cw, cb, Wgt, biasp, cnt);

  gemm_h_csr_mfma<<<1009, 256, 0, stream>>>(x, Wgt, asrc, adst, ei, cnt, csr_src,
                                            Wp, cw, Wqt, hb, sv, tv);

  gat_aggregate_kernel<<<20000, 256, 0, stream>>>(hb, sv, tv, bg, cnt, csr_src, hrelb);

  gemm_fused_mfma<<<640, 256, 0, stream>>>(hrelb, Wqt, biasp, out);
}

// Round 13
// 122.104 us; speedup vs baseline: 1.0358x; 1.0358x over previous
//
#include <hip/hip_runtime.h>
#include <hip/hip_bf16.h>
#include <cstdint>
#include <cstddef>

constexpr int kN = 10000;   // nodes
constexpr int kE = 320000;  // edges
constexpr int kM = 4;       // modalities
constexpr int kD = 256;     // feature dim
constexpr int kP = 256;     // pro dim
constexpr float kSlope = 0.2f;
constexpr int kCap = 96;    // CSR capacity/node: deg ~ Poisson(32), 96 = +11 sigma

typedef __attribute__((ext_vector_type(8))) short bf16x8;
typedef __attribute__((ext_vector_type(4))) float f32x4;
typedef __attribute__((ext_vector_type(2))) float f32x2;

__device__ __forceinline__ unsigned short f2bf(float f) {
  union { float ff; unsigned int i; } v; v.ff = f;
  unsigned int x = v.i;
  unsigned int r = x + 0x7fffu + ((x >> 16) & 1u);
  return (unsigned short)(r >> 16);
}
__device__ __forceinline__ uint4 pack8(float4 a, float4 b) {
  uint4 o;
  o.x = (unsigned)f2bf(a.x) | ((unsigned)f2bf(a.y) << 16);
  o.y = (unsigned)f2bf(a.z) | ((unsigned)f2bf(a.w) << 16);
  o.z = (unsigned)f2bf(b.x) | ((unsigned)f2bf(b.y) << 16);
  o.w = (unsigned)f2bf(b.z) | ((unsigned)f2bf(b.w) << 16);
  return o;
}
__device__ __forceinline__ void gload_lds16(const void* g, void* l) {
  __builtin_amdgcn_global_load_lds((const __attribute__((address_space(1))) unsigned int*)g,
                                   (__attribute__((address_space(3))) unsigned int*)l, 16, 0, 0);
}

// ---------------- weight prep (critical-path only): Wgt + biasp + cnt ----------

__global__ __launch_bounds__(256) void weight_prep_kernel(
    const float* __restrict__ Wg, const float* __restrict__ bp,
    const float* __restrict__ cw, const float* __restrict__ cb,
    unsigned short* __restrict__ Wgt, float* __restrict__ biasp, int* __restrict__ cnt) {
  const int blk = blockIdx.x;
  if (blk >= 65) {
    int z = blk - 65;
    int t = threadIdx.x;
    if (t < 250) ((int4*)cnt)[z * 250 + t] = make_int4(0, 0, 0, 0);
    return;
  }
  if (blk == 64) {
    int p = threadIdx.x;
    float v = cb[0];
#pragma unroll
    for (int mm = 0; mm < kM; mm++) v += cw[mm] * bp[mm * kP + p];
    biasp[p] = v;
    return;
  }
  __shared__ float tile[64][65];
  const int m = blk >> 4;
  const int t2 = blk & 15;
  const int r0 = (t2 >> 2) * 64;
  const int c0 = (t2 & 3) * 64;
  const float* in = Wg + ((size_t)m << 16);
#pragma unroll
  for (int l = 0; l < 16; l++) {
    int idx = l * 256 + threadIdx.x;
    int rr = idx >> 6, cc = idx & 63;
    tile[rr][cc] = in[(size_t)(c0 + rr) * 256 + r0 + cc];
  }
  __syncthreads();
#pragma unroll
  for (int l = 0; l < 16; l++) {
    int idx = l * 256 + threadIdx.x;
    int rr = idx >> 6, cc = idx & 63;
    Wgt[((size_t)m << 16) + (size_t)(r0 + rr) * 256 + c0 + cc] = f2bf(tile[cc][rr]);
  }
}

// ---------------- GEMM 1 (MFMA, A-only LDS dbuf, B direct from L2) + CSR + Wqt --
// blocks [0,632):    hb = bf16(x @ Wg), fused s,t epilogue (m -> XCD pair {2m,2m+1})
// blocks [632,945):  capacity-CSR edge fill
// blocks [945,1009): Wqt transpose (consumed only by gemm_fused)
// B (Wgt, 512 KB) is L2-resident: fragments loaded directly from global --
// removes the 4x gload_lds/thread B staging and halves LDS (41 KB -> ~19 KB).

constexpr int ASTR = 64 * 8 + 8;    // A slot stride (elements), 520
constexpr int kAsBytes = 2 * 4 * ASTR * 2;   // 8320 B
constexpr int kSmemBytes = 64 * 65 * 4;      // 16640 B (Wqt transpose tile) > kAsBytes

__global__ __launch_bounds__(256) void gemm_h_csr_mfma(
    const float* __restrict__ x, const unsigned short* __restrict__ Wgt,
    const float* __restrict__ asrc, const float* __restrict__ adst,
    const int* __restrict__ ei, int* __restrict__ cnt, int* __restrict__ csr_src,
    const float* __restrict__ Wp, const float* __restrict__ cw,
    unsigned short* __restrict__ Wqt,
    unsigned short* __restrict__ hb, float* __restrict__ sv, float* __restrict__ tv) {
  const int blk = blockIdx.x;
  const int tid = threadIdx.x;

  __shared__ __align__(16) char smem[kSmemBytes];
  __shared__ float sred[256], tred[256];
  auto As = (unsigned short(*)[4 * ASTR])smem;   // [2][4*ASTR]

  if (blk >= 945) {
    auto tile = (float(*)[65])smem;
    const int b = blk - 945;
    const int m = b >> 4;
    const int t2 = b & 15;
    const int r0 = (t2 >> 2) * 64;
    const int c0 = (t2 & 3) * 64;
    const float* in = Wp + ((size_t)m << 16);
    const float scale = cw[m];
#pragma unroll
    for (int l = 0; l < 16; l++) {
      int idx = l * 256 + tid;
      int rr = idx >> 6, cc = idx & 63;
      tile[rr][cc] = in[(size_t)(c0 + rr) * 256 + r0 + cc] * scale;
    }
    __syncthreads();
#pragma unroll
    for (int l = 0; l < 16; l++) {
      int idx = l * 256 + tid;
      int rr = idx >> 6, cc = idx & 63;
      Wqt[(size_t)(r0 + rr) * 1024 + (m << 8) + c0 + cc] = f2bf(tile[cc][rr]);
    }
    return;
  }

  if (blk >= 632) {
    int t = (blk - 632) * 256 + tid;
    int e4 = t * 4;
    if (e4 >= kE) return;
    int4 s4 = *(const int4*)&ei[e4];
    int4 d4 = *(const int4*)&ei[kE + e4];
    int sl;
    sl = atomicAdd(&cnt[d4.x], 1); csr_src[d4.x * kCap + sl] = s4.x;
    sl = atomicAdd(&cnt[d4.y], 1); csr_src[d4.y * kCap + sl] = s4.y;
    sl = atomicAdd(&cnt[d4.z], 1); csr_src[d4.z * kCap + sl] = s4.z;
    sl = atomicAdd(&cnt[d4.w], 1); csr_src[d4.w * kCap + sl] = s4.w;
    return;
  }

  // m -> XCD pair {2m, 2m+1}
  const int m = (blk & 7) >> 1;
  const int i = (blk >> 3) * 2 + (blk & 1);
  if (i >= 157) return;
  const int row0 = i * 64;

  const int wave = tid >> 6, lane = tid & 63;
  const int lidx = lane & 15, lslot = lane >> 4;
  const int wcol0 = wave * 64;

  const int arow_s = tid & 63, aslot_s = tid >> 6;
  const int agr = min(row0 + arow_s, kN - 1);
  const float* Abase = x + ((size_t)m * kN + agr) * kD + aslot_s * 8;
  // per-lane B base: column (wcol0 + lidx), k-offset lslot*8
  const unsigned short* Bcol = Wgt + (size_t)m * kD * kD + (size_t)(wcol0 + lidx) * kD + lslot * 8;

  f32x4 acc[4][4] = {};

  {
    float4 f0 = *(const float4*)(Abase);
    float4 f1 = *(const float4*)(Abase + 4);
    *(uint4*)&As[0][aslot_s * ASTR + arow_s * 8] = pack8(f0, f1);
  }
  __syncthreads();

  int buf = 0;
  for (int t = 0; t < 8; t++) {
    const int k0 = t * 32;
    float4 f0, f1;
    const bool pf = (t < 7);
    if (pf) {
      f0 = *(const float4*)(Abase + k0 + 32);
      f1 = *(const float4*)(Abase + k0 + 36);
    }
    // B fragments direct from global (L2-resident Wgt)
    bf16x8 bfr[4];
#pragma unroll
    for (int j = 0; j < 4; j++)
      bfr[j] = *(const bf16x8*)(Bcol + (size_t)(j * 16) * kD + k0);
    bf16x8 a[4];
#pragma unroll
    for (int i2 = 0; i2 < 4; i2++)
      a[i2] = *(const bf16x8*)&As[buf][lslot * ASTR + (i2 * 16 + lidx) * 8];
#pragma unroll
    for (int i2 = 0; i2 < 4; i2++)
#pragma unroll
      for (int j = 0; j < 4; j++)
        acc[i2][j] = __builtin_amdgcn_mfma_f32_16x16x32_bf16(a[i2], bfr[j], acc[i2][j], 0, 0, 0);
    if (pf) {
      *(uint4*)&As[buf ^ 1][aslot_s * ASTR + arow_s * 8] = pack8(f0, f1);
    }
    __syncthreads();
    buf ^= 1;
  }

  // epilogue: store hb + fused s,t dot products
  const int slot4 = lane >> 4;
  float av[4], dv[4];
#pragma unroll
  for (int j = 0; j < 4; j++) {
    av[j] = asrc[m * kD + wcol0 + j * 16 + lidx];
    dv[j] = adst[m * kD + wcol0 + j * 16 + lidx];
  }
#pragma unroll
  for (int i2 = 0; i2 < 4; i2++) {
#pragma unroll
    for (int reg = 0; reg < 4; reg++) {
      int grow = row0 + i2 * 16 + slot4 * 4 + reg;
      float sp = 0.f, tp = 0.f;
#pragma unroll
      for (int j = 0; j < 4; j++) {
        float hv = acc[i2][j][reg];
        sp += hv * av[j];
        tp += hv * dv[j];
        if (grow < kN) hb[((size_t)m * kN + grow) * kD + wcol0 + j * 16 + lidx] = f2bf(hv);
      }
#pragma unroll
      for (int o = 1; o < 16; o <<= 1) {
        sp += __shfl_xor(sp, o);
        tp += __shfl_xor(tp, o);
      }
      if (lidx == 0) {
        sred[wave * 64 + i2 * 16 + slot4 * 4 + reg] = sp;
        tred[wave * 64 + i2 * 16 + slot4 * 4 + reg] = tp;
      }
    }
  }
  __syncthreads();
  if (tid < 64) {
    int grow = row0 + tid;
    if (grow < kN) {
      float s = sred[tid] + sred[64 + tid] + sred[128 + tid] + sred[192 + tid];
      float t = tred[tid] + tred[64 + tid] + tred[128 + tid] + tred[192 + tid];
      sv[m * kN + grow] = s;
      tv[m * kN + grow] = t;
    }
  }
}

// ---------------- GAT softmax + aggregate (capacity CSR) -- R10 operating point -
// Wave per (m,n); modality->XCD affinity; edges in pairs (half-wave x 16B),
// 8 edges / 4 gathers in flight per inner iter (VGPR 36, occupancy ~57%).

__global__ __launch_bounds__(256) void gat_aggregate_kernel(
    const unsigned short* __restrict__ hb, const float* __restrict__ sv,
    const float* __restrict__ tv, const float* __restrict__ bg,
    const int* __restrict__ cnt, const int* __restrict__ csr_src,
    unsigned short* __restrict__ hrelb) {
  const int l = blockIdx.x;
  const int xcd = l & 7;
  const int m = xcd >> 1;
  const int ngroup = (l >> 3) * 2 + (xcd & 1);   // [0, 2500)
  const int n = ngroup * 4 + (threadIdx.x >> 6);
  const int lane = threadIdx.x & 63;
  const int half = lane >> 5;
  const int lf = lane & 31;
  const int fb = lf * 8;

  const float tt = tv[m * kN + n];
  const int b = n * kCap;
  const int deg = cnt[n];

  float a_self = sv[m * kN + n] + tt;
  a_self = fmaxf(a_self, kSlope * a_self);
  const float e_self = __expf(a_self);

  const unsigned short* hm = hb + ((size_t)m * kN << 8) + fb;
  f32x2 acc2[4] = {};
  {
    const float es = half ? 0.f : e_self;
    const f32x2 es2 = {es, es};
    uint4 hx = *(const uint4*)(hm + ((size_t)n << 8));
#pragma unroll
    for (int q = 0; q < 4; q++) {
      unsigned w = ((const unsigned*)&hx)[q];
      f32x2 hv2 = {__uint_as_float(w << 16), __uint_as_float(w & 0xffff0000u)};
      acc2[q] = __builtin_elementwise_fma(hv2, es2, acc2[q]);
    }
  }
  float denom = (lane == 0) ? e_self : 0.f;

  for (int c0 = 0; c0 < deg; c0 += 64) {
    int j = c0 + lane;
    float ee = 0.f;
    int src = 0;
    if (j < deg) {
      src = csr_src[b + j];
      float a = sv[m * kN + src] + tt;
      a = fmaxf(a, kSlope * a);
      ee = __expf(a);
    }
    denom += ee;
    const int cl = min(64, deg - c0);
    for (int j2 = 0; j2 < cl; j2 += 8) {
#pragma unroll
      for (int p = 0; p < 4; p++) {
        int ja = j2 + 2 * p;
        float ep = __shfl(ee, ja + half);
        int sp = __shfl(src, ja + half);
        uint4 hx = *(const uint4*)(hm + ((size_t)sp << 8));
        const f32x2 ep2 = {ep, ep};
#pragma unroll
        for (int q = 0; q < 4; q++) {
          unsigned w = ((const unsigned*)&hx)[q];
          f32x2 hv2 = {__uint_as_float(w << 16), __uint_as_float(w & 0xffff0000u)};
          acc2[q] = __builtin_elementwise_fma(hv2, ep2, acc2[q]);
        }
      }
    }
  }
#pragma unroll
  for (int o = 32; o > 0; o >>= 1) denom += __shfl_xor(denom, o);
  const float inv = 1.f / (denom + 1e-16f);

#pragma unroll
  for (int q = 0; q < 4; q++) {
    acc2[q].x += __shfl_xor(acc2[q].x, 32);
    acc2[q].y += __shfl_xor(acc2[q].y, 32);
  }

  if (half == 0) {
    const float* bgp = bg + m * kD + fb;
    float4 b0 = *(const float4*)bgp;
    float4 b1 = *(const float4*)(bgp + 4);
    float4 o0, o1;
    o0.x = fmaxf(acc2[0].x * inv + b0.x, 0.f);
    o0.y = fmaxf(acc2[0].y * inv + b0.y, 0.f);
    o0.z = fmaxf(acc2[1].x * inv + b0.z, 0.f);
    o0.w = fmaxf(acc2[1].y * inv + b0.w, 0.f);
    o1.x = fmaxf(acc2[2].x * inv + b1.x, 0.f);
    o1.y = fmaxf(acc2[2].y * inv + b1.y, 0.f);
    o1.z = fmaxf(acc2[3].x * inv + b1.z, 0.f);
    o1.w = fmaxf(acc2[3].y * inv + b1.w, 0.f);
    *(uint4*)(hrelb + (((size_t)m * kN + n) << 8) + fb) = pack8(o0, o1);
  }
}

// ---------------- GEMM 2 (MFMA, A-only LDS dbuf, B direct from L2) -------------
// out = hrelb([N,1024]) @ Wqt + biasp. Wqt (512 KB) is L2-resident: B fragments
// loaded directly from global; only A (hrelb rows) staged via gload_lds dbuf.

constexpr int FSTR = 64 * 8 + 8;

__global__ __launch_bounds__(256) void gemm_fused_mfma(const unsigned short* __restrict__ hrelb,
                                                       const unsigned short* __restrict__ Wqt,
                                                       const float* __restrict__ biasp,
                                                       float* __restrict__ out) {
  const int l = blockIdx.x;
  const int xcd = l & 7;
  const int t0 = l >> 3;
  const int c = t0 & 3;
  const int r = (t0 >> 2) * 8 + xcd;
  if (r >= 157) return;
  const int row0 = r * 64;
  const int col0 = c * 64;

  const int tid = threadIdx.x;
  const int wave = tid >> 6, lane = tid & 63;
  const int lidx = lane & 15, lslot = lane >> 4;
  const int wr = wave >> 1, wc = wave & 1;

  __shared__ __align__(16) unsigned short As[2][8 * FSTR];

  f32x4 acc[2][2] = {};

  const int arow = min(row0 + (tid & 63), kN - 1);
  // per-lane B base: column col0 + wc*32 + lidx
  const unsigned short* Bcol = Wqt + (size_t)(col0 + wc * 32 + lidx) * 1024;

#pragma unroll
  for (int ll = 0; ll < 2; ll++) {
    int slot = (tid >> 6) + ll * 4;
    gload_lds16(hrelb + ((size_t)arow << 8) + slot * 8,
                &As[0][slot * FSTR + (tid & 63) * 8]);
  }
  __syncthreads();

  int buf = 0;
  for (int t = 0; t < 16; t++) {
    const int k0 = t * 64;
    if (t < 15) {
      const int k1 = k0 + 64;
      const int mm = k1 >> 8;
      const int d1 = k1 & 255;
#pragma unroll
      for (int ll = 0; ll < 2; ll++) {
        int slot = (tid >> 6) + ll * 4;
        gload_lds16(hrelb + (((size_t)mm * kN + arow) << 8) + d1 + slot * 8,
                    &As[buf ^ 1][slot * FSTR + (tid & 63) * 8]);
      }
    }
#pragma unroll
    for (int s = 0; s < 2; s++) {
      const int ks = s * 4 + lslot;
      bf16x8 a[2], bfr[2];
#pragma unroll
      for (int i = 0; i < 2; i++)
        a[i] = *(const bf16x8*)&As[buf][ks * FSTR + (wr * 32 + i * 16 + lidx) * 8];
#pragma unroll
      for (int j = 0; j < 2; j++)
        bfr[j] = *(const bf16x8*)(Bcol + (size_t)(j * 16) * 1024 + k0 + ks * 8);
#pragma unroll
      for (int i = 0; i < 2; i++)
#pragma unroll
        for (int j = 0; j < 2; j++)
          acc[i][j] = __builtin_amdgcn_mfma_f32_16x16x32_bf16(a[i], bfr[j], acc[i][j], 0, 0, 0);
    }
    __syncthreads();
    buf ^= 1;
  }

  const int slot4 = lane >> 4;
#pragma unroll
  for (int i = 0; i < 2; i++) {
#pragma unroll
    for (int reg = 0; reg < 4; reg++) {
      int grow = row0 + wr * 32 + i * 16 + slot4 * 4 + reg;
      if (grow < kN) {
#pragma unroll
        for (int j = 0; j < 2; j++) {
          int gcol = col0 + wc * 32 + j * 16 + lidx;
          out[(size_t)grow * kP + gcol] = acc[i][j][reg] + biasp[gcol];
        }
      }
    }
  }
}

// ---------------- host launch ----------------

extern "C" void kernel_launch(void* const* d_in, const int* in_sizes, int n_in,
                              void* d_out, int out_size, void* d_ws, size_t ws_size,
                              hipStream_t stream) {
  const float* x = (const float*)d_in[0];
  const int* ei = (const int*)d_in[1];
  const float* Wg = (const float*)d_in[2];
  const float* asrc = (const float*)d_in[3];
  const float* adst = (const float*)d_in[4];
  const float* bg = (const float*)d_in[5];
  const float* Wp = (const float*)d_in[6];
  const float* bp = (const float*)d_in[7];
  const float* cw = (const float*)d_in[8];
  const float* cb = (const float*)d_in[9];
  float* out = (float*)d_out;

  char* ws = (char*)d_ws;
  size_t off = 0;
  auto alloc = [&](size_t bytes) -> void* {
    void* p = ws + off;
    off = (off + bytes + 255) & ~(size_t)255;
    return p;
  };
  unsigned short* hb = (unsigned short*)alloc((size_t)kM * kN * kD * 2);
  unsigned short* hrelb = (unsigned short*)alloc((size_t)kM * kN * kD * 2);
  unsigned short* Wgt = (unsigned short*)alloc((size_t)kM * kD * kD * 2);
  unsigned short* Wqt = (unsigned short*)alloc((size_t)kP * kM * kD * 2);
  float* sv = (float*)alloc((size_t)kM * kN * sizeof(float));
  float* tv = (float*)alloc((size_t)kM * kN * sizeof(float));
  float* biasp = (float*)alloc(kP * sizeof(float));
  int* cnt = (int*)alloc(kN * sizeof(int));
  int* csr_src = (int*)alloc((size_t)kN * kCap * sizeof(int));

  weight_prep_kernel<<<75, 256, 0, stream>>>(Wg, bp, cw, cb, Wgt, biasp, cnt);

  gemm_h_csr_mfma<<<1009, 256, 0, stream>>>(x, Wgt, asrc, adst, ei, cnt, csr_src,
                                            Wp, cw, Wqt, hb, sv, tv);

  gat_aggregate_kernel<<<kN, 256, 0, stream>>>(hb, sv, tv, bg, cnt, csr_src, hrelb);

  gemm_fused_mfma<<<640, 256, 0, stream>>>(hrelb, Wqt, biasp, out);
}

// Round 14
// 114.378 us; speedup vs baseline: 1.1058x; 1.0675x over previous
//
#include <hip/hip_runtime.h>
#include <hip/hip_bf16.h>
#include <cstdint>
#include <cstddef>

constexpr int kN = 10000;   // nodes
constexpr int kE = 320000;  // edges
constexpr int kM = 4;       // modalities
constexpr int kD = 256;     // feature dim
constexpr int kP = 256;     // pro dim
constexpr float kSlope = 0.2f;
constexpr int kCap = 96;    // CSR capacity/node: deg ~ Poisson(32), 96 = +11 sigma

typedef __attribute__((ext_vector_type(8))) short bf16x8;
typedef __attribute__((ext_vector_type(4))) float f32x4;
typedef __attribute__((ext_vector_type(2))) float f32x2;

__device__ __forceinline__ unsigned short f2bf(float f) {
  union { float ff; unsigned int i; } v; v.ff = f;
  unsigned int x = v.i;
  unsigned int r = x + 0x7fffu + ((x >> 16) & 1u);
  return (unsigned short)(r >> 16);
}
__device__ __forceinline__ uint4 pack8(float4 a, float4 b) {
  uint4 o;
  o.x = (unsigned)f2bf(a.x) | ((unsigned)f2bf(a.y) << 16);
  o.y = (unsigned)f2bf(a.z) | ((unsigned)f2bf(a.w) << 16);
  o.z = (unsigned)f2bf(b.x) | ((unsigned)f2bf(b.y) << 16);
  o.w = (unsigned)f2bf(b.z) | ((unsigned)f2bf(b.w) << 16);
  return o;
}
__device__ __forceinline__ void gload_lds16(const void* g, void* l) {
  __builtin_amdgcn_global_load_lds((const __attribute__((address_space(1))) unsigned int*)g,
                                   (__attribute__((address_space(3))) unsigned int*)l, 16, 0, 0);
}

// ---------------- weight prep (critical-path only): Wgt + biasp + cnt ----------

__global__ __launch_bounds__(256) void weight_prep_kernel(
    const float* __restrict__ Wg, const float* __restrict__ bp,
    const float* __restrict__ cw, const float* __restrict__ cb,
    unsigned short* __restrict__ Wgt, float* __restrict__ biasp, int* __restrict__ cnt) {
  const int blk = blockIdx.x;
  if (blk >= 65) {
    int z = blk - 65;
    int t = threadIdx.x;
    if (t < 250) ((int4*)cnt)[z * 250 + t] = make_int4(0, 0, 0, 0);
    return;
  }
  if (blk == 64) {
    int p = threadIdx.x;
    float v = cb[0];
#pragma unroll
    for (int mm = 0; mm < kM; mm++) v += cw[mm] * bp[mm * kP + p];
    biasp[p] = v;
    return;
  }
  __shared__ float tile[64][65];
  const int m = blk >> 4;
  const int t2 = blk & 15;
  const int r0 = (t2 >> 2) * 64;
  const int c0 = (t2 & 3) * 64;
  const float* in = Wg + ((size_t)m << 16);
#pragma unroll
  for (int l = 0; l < 16; l++) {
    int idx = l * 256 + threadIdx.x;
    int rr = idx >> 6, cc = idx & 63;
    tile[rr][cc] = in[(size_t)(c0 + rr) * 256 + r0 + cc];
  }
  __syncthreads();
#pragma unroll
  for (int l = 0; l < 16; l++) {
    int idx = l * 256 + threadIdx.x;
    int rr = idx >> 6, cc = idx & 63;
    Wgt[((size_t)m << 16) + (size_t)(r0 + rr) * 256 + c0 + cc] = f2bf(tile[cc][rr]);
  }
}

// ---------------- GEMM 1 (MFMA + full LDS staging, 2-phase dbuf) + CSR + Wqt ----
// blocks [0,632):    hb = bf16(x @ Wg), fused s,t epilogue (m -> XCD pair {2m,2m+1})
// blocks [632,945):  capacity-CSR edge fill
// blocks [945,1009): Wqt transpose (consumed only by gemm_fused)

constexpr int ASTR = 64 * 8 + 8;    // A slot stride (elements)
constexpr int BSTR = 256 * 8 + 8;   // B slot stride (elements)
constexpr int kAsBytes = 2 * 4 * ASTR * 2;
constexpr int kBsBytes = 2 * 4 * BSTR * 2;

__global__ __launch_bounds__(256) void gemm_h_csr_mfma(
    const float* __restrict__ x, const unsigned short* __restrict__ Wgt,
    const float* __restrict__ asrc, const float* __restrict__ adst,
    const int* __restrict__ ei, int* __restrict__ cnt, int* __restrict__ csr_src,
    const float* __restrict__ Wp, const float* __restrict__ cw,
    unsigned short* __restrict__ Wqt,
    unsigned short* __restrict__ hb, float* __restrict__ sv, float* __restrict__ tv) {
  const int blk = blockIdx.x;
  const int tid = threadIdx.x;

  __shared__ __align__(16) char smem[kAsBytes + kBsBytes];
  __shared__ float sred[256], tred[256];
  auto As = (unsigned short(*)[4 * ASTR])smem;
  auto Bs = (unsigned short(*)[4 * BSTR])(smem + kAsBytes);

  if (blk >= 945) {
    auto tile = (float(*)[65])smem;
    const int b = blk - 945;
    const int m = b >> 4;
    const int t2 = b & 15;
    const int r0 = (t2 >> 2) * 64;
    const int c0 = (t2 & 3) * 64;
    const float* in = Wp + ((size_t)m << 16);
    const float scale = cw[m];
#pragma unroll
    for (int l = 0; l < 16; l++) {
      int idx = l * 256 + tid;
      int rr = idx >> 6, cc = idx & 63;
      tile[rr][cc] = in[(size_t)(c0 + rr) * 256 + r0 + cc] * scale;
    }
    __syncthreads();
#pragma unroll
    for (int l = 0; l < 16; l++) {
      int idx = l * 256 + tid;
      int rr = idx >> 6, cc = idx & 63;
      Wqt[(size_t)(r0 + rr) * 1024 + (m << 8) + c0 + cc] = f2bf(tile[cc][rr]);
    }
    return;
  }

  if (blk >= 632) {
    int t = (blk - 632) * 256 + tid;
    int e4 = t * 4;
    if (e4 >= kE) return;
    int4 s4 = *(const int4*)&ei[e4];
    int4 d4 = *(const int4*)&ei[kE + e4];
    int sl;
    sl = atomicAdd(&cnt[d4.x], 1); csr_src[d4.x * kCap + sl] = s4.x;
    sl = atomicAdd(&cnt[d4.y], 1); csr_src[d4.y * kCap + sl] = s4.y;
    sl = atomicAdd(&cnt[d4.z], 1); csr_src[d4.z * kCap + sl] = s4.z;
    sl = atomicAdd(&cnt[d4.w], 1); csr_src[d4.w * kCap + sl] = s4.w;
    return;
  }

  // m -> XCD pair {2m, 2m+1}
  const int m = (blk & 7) >> 1;
  const int i = (blk >> 3) * 2 + (blk & 1);
  if (i >= 157) return;
  const int row0 = i * 64;

  const int wave = tid >> 6, lane = tid & 63;
  const int lidx = lane & 15, lslot = lane >> 4;
  const int wcol0 = wave * 64;

  const int arow_s = tid & 63, aslot_s = tid >> 6;
  const int agr = min(row0 + arow_s, kN - 1);
  const float* Abase = x + ((size_t)m * kN + agr) * kD + aslot_s * 8;
  const unsigned short* Bbase = Wgt + (size_t)m * kD * kD;

  f32x4 acc[4][4] = {};

  {
    float4 f0 = *(const float4*)(Abase);
    float4 f1 = *(const float4*)(Abase + 4);
    *(uint4*)&As[0][aslot_s * ASTR + arow_s * 8] = pack8(f0, f1);
#pragma unroll
    for (int l = 0; l < 4; l++) {
      int c = tid + l * 256;
      int col = c & 255, slot = c >> 8;
      gload_lds16(Bbase + (size_t)col * kD + slot * 8, &Bs[0][slot * BSTR + col * 8]);
    }
  }
  __syncthreads();

  int buf = 0;
  for (int t = 0; t < 8; t++) {
    float4 f0, f1;
    const bool pf = (t < 7);
    if (pf) {
      const int k1 = (t + 1) * 32;
      f0 = *(const float4*)(Abase + k1);
      f1 = *(const float4*)(Abase + k1 + 4);
#pragma unroll
      for (int l = 0; l < 4; l++) {
        int c = tid + l * 256;
        int col = c & 255, slot = c >> 8;
        gload_lds16(Bbase + (size_t)col * kD + k1 + slot * 8,
                    &Bs[buf ^ 1][slot * BSTR + col * 8]);
      }
    }
    bf16x8 a[4], bfr[4];
#pragma unroll
    for (int i2 = 0; i2 < 4; i2++)
      a[i2] = *(const bf16x8*)&As[buf][lslot * ASTR + (i2 * 16 + lidx) * 8];
#pragma unroll
    for (int j = 0; j < 4; j++)
      bfr[j] = *(const bf16x8*)&Bs[buf][lslot * BSTR + (wcol0 + j * 16 + lidx) * 8];
#pragma unroll
    for (int i2 = 0; i2 < 4; i2++)
#pragma unroll
      for (int j = 0; j < 4; j++)
        acc[i2][j] = __builtin_amdgcn_mfma_f32_16x16x32_bf16(a[i2], bfr[j], acc[i2][j], 0, 0, 0);
    if (pf) {
      *(uint4*)&As[buf ^ 1][aslot_s * ASTR + arow_s * 8] = pack8(f0, f1);
    }
    __syncthreads();
    buf ^= 1;
  }

  // epilogue: store hb + fused s,t dot products
  const int slot4 = lane >> 4;
  float av[4], dv[4];
#pragma unroll
  for (int j = 0; j < 4; j++) {
    av[j] = asrc[m * kD + wcol0 + j * 16 + lidx];
    dv[j] = adst[m * kD + wcol0 + j * 16 + lidx];
  }
#pragma unroll
  for (int i2 = 0; i2 < 4; i2++) {
#pragma unroll
    for (int reg = 0; reg < 4; reg++) {
      int grow = row0 + i2 * 16 + slot4 * 4 + reg;
      float sp = 0.f, tp = 0.f;
#pragma unroll
      for (int j = 0; j < 4; j++) {
        float hv = acc[i2][j][reg];
        sp += hv * av[j];
        tp += hv * dv[j];
        if (grow < kN) hb[((size_t)m * kN + grow) * kD + wcol0 + j * 16 + lidx] = f2bf(hv);
      }
#pragma unroll
      for (int o = 1; o < 16; o <<= 1) {
        sp += __shfl_xor(sp, o);
        tp += __shfl_xor(tp, o);
      }
      if (lidx == 0) {
        sred[wave * 64 + i2 * 16 + slot4 * 4 + reg] = sp;
        tred[wave * 64 + i2 * 16 + slot4 * 4 + reg] = tp;
      }
    }
  }
  __syncthreads();
  if (tid < 64) {
    int grow = row0 + tid;
    if (grow < kN) {
      float s = sred[tid] + sred[64 + tid] + sred[128 + tid] + sred[192 + tid];
      float t = tred[tid] + tred[64 + tid] + tred[128 + tid] + tred[192 + tid];
      sv[m * kN + grow] = s;
      tv[m * kN + grow] = t;
    }
  }
}

// ---------------- GAT softmax + aggregate (capacity CSR) ----------------
// Wave per (m,n); modality->XCD affinity; edges in pairs (half-wave x 16B).
// NEW inner loop: per-wave LDS edge buffer {ee, src<<9} replaces 2x __shfl
// (ds_read_b64 at base+imm offset, zero index math); gathers use uniform
// SGPR base + 32-bit byte voffset (no per-edge 64-bit address arithmetic).

__global__ __launch_bounds__(256) void gat_aggregate_kernel(
    const unsigned short* __restrict__ hb, const float* __restrict__ sv,
    const float* __restrict__ tv, const float* __restrict__ bg,
    const int* __restrict__ cnt, const int* __restrict__ csr_src,
    unsigned short* __restrict__ hrelb) {
  const int l = blockIdx.x;
  const int xcd = l & 7;
  const int m = xcd >> 1;
  const int ngroup = (l >> 3) * 2 + (xcd & 1);   // [0, 2500)
  const int wv = threadIdx.x >> 6;
  const int n = ngroup * 4 + wv;
  const int lane = threadIdx.x & 63;
  const int half = lane >> 5;
  const int lf = lane & 31;
  const int fb = lf * 8;                 // feature offset in shorts (for output)
  const unsigned fbyte = (unsigned)lf * 16u;  // feature offset in bytes

  __shared__ uint2 ebuf[4][64];          // per-wave edge strip: {ee bits, src*512}

  const float tt = tv[m * kN + n];
  const int b = n * kCap;
  const int deg = cnt[n];

  float a_self = sv[m * kN + n] + tt;
  a_self = fmaxf(a_self, kSlope * a_self);
  const float e_self = __expf(a_self);

  const char* hmB = (const char*)(hb + ((size_t)m * kN << 8));  // uniform per wave

  f32x2 acc2[4] = {};
  {
    const float es = half ? 0.f : e_self;
    const f32x2 es2 = {es, es};
    uint4 hx = *(const uint4*)(hmB + (((unsigned)n << 9) + fbyte));
#pragma unroll
    for (int q = 0; q < 4; q++) {
      unsigned w = ((const unsigned*)&hx)[q];
      f32x2 hv2 = {__uint_as_float(w << 16), __uint_as_float(w & 0xffff0000u)};
      acc2[q] = __builtin_elementwise_fma(hv2, es2, acc2[q]);
    }
  }
  float denom = (lane == 0) ? e_self : 0.f;

  for (int c0 = 0; c0 < deg; c0 += 64) {
    int j = c0 + lane;
    float ee = 0.f;
    unsigned soff = 0;
    if (j < deg) {
      int src = csr_src[b + j];
      float a = sv[m * kN + src] + tt;
      a = fmaxf(a, kSlope * a);
      ee = __expf(a);
      soff = (unsigned)src << 9;         // byte offset of source row
    }
    denom += ee;
    ebuf[wv][lane] = make_uint2(__float_as_uint(ee), soff);
    // same-wave LDS RAW: compiler inserts lgkmcnt wait, no barrier needed
    const int cl = min(64, deg - c0);
    const uint2* ebase = &ebuf[wv][half];  // half 0 -> even edge, half 1 -> odd
    for (int j2 = 0; j2 < cl; j2 += 8) {
#pragma unroll
      for (int p = 0; p < 4; p++) {
        uint2 es_ = ebase[j2 + 2 * p];     // ds_read_b64, imm offset
        float ep = __uint_as_float(es_.x);
        uint4 hx = *(const uint4*)(hmB + (es_.y + fbyte));  // saddr + 32b voffset
        const f32x2 ep2 = {ep, ep};
#pragma unroll
        for (int q = 0; q < 4; q++) {
          unsigned w = ((const unsigned*)&hx)[q];
          f32x2 hv2 = {__uint_as_float(w << 16), __uint_as_float(w & 0xffff0000u)};
          acc2[q] = __builtin_elementwise_fma(hv2, ep2, acc2[q]);
        }
      }
    }
  }
#pragma unroll
  for (int o = 32; o > 0; o >>= 1) denom += __shfl_xor(denom, o);
  const float inv = 1.f / (denom + 1e-16f);

  // merge halves: lane L + lane L^32 hold partial sums of the same features
#pragma unroll
  for (int q = 0; q < 4; q++) {
    acc2[q].x += __shfl_xor(acc2[q].x, 32);
    acc2[q].y += __shfl_xor(acc2[q].y, 32);
  }

  if (half == 0) {
    const float* bgp = bg + m * kD + fb;
    float4 b0 = *(const float4*)bgp;
    float4 b1 = *(const float4*)(bgp + 4);
    float4 o0, o1;
    o0.x = fmaxf(acc2[0].x * inv + b0.x, 0.f);
    o0.y = fmaxf(acc2[0].y * inv + b0.y, 0.f);
    o0.z = fmaxf(acc2[1].x * inv + b0.z, 0.f);
    o0.w = fmaxf(acc2[1].y * inv + b0.w, 0.f);
    o1.x = fmaxf(acc2[2].x * inv + b1.x, 0.f);
    o1.y = fmaxf(acc2[2].y * inv + b1.y, 0.f);
    o1.z = fmaxf(acc2[3].x * inv + b1.z, 0.f);
    o1.w = fmaxf(acc2[3].y * inv + b1.w, 0.f);
    *(uint4*)(hrelb + (((size_t)m * kN + n) << 8) + fb) = pack8(o0, o1);
  }
}

// ---------------- GEMM 2 (MFMA + full LDS staging, 2-phase dbuf) ----------------

constexpr int FSTR = 64 * 8 + 8;

__global__ __launch_bounds__(256) void gemm_fused_mfma(const unsigned short* __restrict__ hrelb,
                                                       const unsigned short* __restrict__ Wqt,
                                                       const float* __restrict__ biasp,
                                                       float* __restrict__ out) {
  const int l = blockIdx.x;
  const int xcd = l & 7;
  const int t0 = l >> 3;
  const int c = t0 & 3;
  const int r = (t0 >> 2) * 8 + xcd;
  if (r >= 157) return;
  const int row0 = r * 64;
  const int col0 = c * 64;

  const int tid = threadIdx.x;
  const int wave = tid >> 6, lane = tid & 63;
  const int lidx = lane & 15, lslot = lane >> 4;
  const int wr = wave >> 1, wc = wave & 1;

  __shared__ __align__(16) unsigned short As[2][8 * FSTR];
  __shared__ __align__(16) unsigned short Bs[2][8 * FSTR];

  f32x4 acc[2][2] = {};

  const int arow = min(row0 + (tid & 63), kN - 1);
  const int bcol = col0 + (tid & 63);

#pragma unroll
  for (int ll = 0; ll < 2; ll++) {
    int slot = (tid >> 6) + ll * 4;
    gload_lds16(hrelb + ((size_t)arow << 8) + slot * 8,
                &As[0][slot * FSTR + (tid & 63) * 8]);
    gload_lds16(Wqt + (size_t)bcol * 1024 + slot * 8,
                &Bs[0][slot * FSTR + (tid & 63) * 8]);
  }
  __syncthreads();

  int buf = 0;
  for (int t = 0; t < 16; t++) {
    if (t < 15) {
      const int k1 = (t + 1) * 64;
      const int mm = k1 >> 8;
      const int d1 = k1 & 255;
#pragma unroll
      for (int ll = 0; ll < 2; ll++) {
        int slot = (tid >> 6) + ll * 4;
        gload_lds16(hrelb + (((size_t)mm * kN + arow) << 8) + d1 + slot * 8,
                    &As[buf ^ 1][slot * FSTR + (tid & 63) * 8]);
        gload_lds16(Wqt + (size_t)bcol * 1024 + k1 + slot * 8,
                    &Bs[buf ^ 1][slot * FSTR + (tid & 63) * 8]);
      }
    }
#pragma unroll
    for (int s = 0; s < 2; s++) {
      const int ks = s * 4 + lslot;
      bf16x8 a[2], bfr[2];
#pragma unroll
      for (int i = 0; i < 2; i++)
        a[i] = *(const bf16x8*)&As[buf][ks * FSTR + (wr * 32 + i * 16 + lidx) * 8];
#pragma unroll
      for (int j = 0; j < 2; j++)
        bfr[j] = *(const bf16x8*)&Bs[buf][ks * FSTR + (wc * 32 + j * 16 + lidx) * 8];
#pragma unroll
      for (int i = 0; i < 2; i++)
#pragma unroll
        for (int j = 0; j < 2; j++)
          acc[i][j] = __builtin_amdgcn_mfma_f32_16x16x32_bf16(a[i], bfr[j], acc[i][j], 0, 0, 0);
    }
    __syncthreads();
    buf ^= 1;
  }

  const int slot4 = lane >> 4;
#pragma unroll
  for (int i = 0; i < 2; i++) {
#pragma unroll
    for (int reg = 0; reg < 4; reg++) {
      int grow = row0 + wr * 32 + i * 16 + slot4 * 4 + reg;
      if (grow < kN) {
#pragma unroll
        for (int j = 0; j < 2; j++) {
          int gcol = col0 + wc * 32 + j * 16 + lidx;
          out[(size_t)grow * kP + gcol] = acc[i][j][reg] + biasp[gcol];
        }
      }
    }
  }
}

// ---------------- host launch ----------------

extern "C" void kernel_launch(void* const* d_in, const int* in_sizes, int n_in,
                              void* d_out, int out_size, void* d_ws, size_t ws_size,
                              hipStream_t stream) {
  const float* x = (const float*)d_in[0];
  const int* ei = (const int*)d_in[1];
  const float* Wg = (const float*)d_in[2];
  const float* asrc = (const float*)d_in[3];
  const float* adst = (const float*)d_in[4];
  const float* bg = (const float*)d_in[5];
  const float* Wp = (const float*)d_in[6];
  const float* bp = (const float*)d_in[7];
  const float* cw = (const float*)d_in[8];
  const float* cb = (const float*)d_in[9];
  float* out = (float*)d_out;

  char* ws = (char*)d_ws;
  size_t off = 0;
  auto alloc = [&](size_t bytes) -> void* {
    void* p = ws + off;
    off = (off + bytes + 255) & ~(size_t)255;
    return p;
  };
  unsigned short* hb = (unsigned short*)alloc((size_t)kM * kN * kD * 2);
  unsigned short* hrelb = (unsigned short*)alloc((size_t)kM * kN * kD * 2);
  unsigned short* Wgt = (unsigned short*)alloc((size_t)kM * kD * kD * 2);
  unsigned short* Wqt = (unsigned short*)alloc((size_t)kP * kM * kD * 2);
  float* sv = (float*)alloc((size_t)kM * kN * sizeof(float));
  float* tv = (float*)alloc((size_t)kM * kN * sizeof(float));
  float* biasp = (float*)alloc(kP * sizeof(float));
  int* cnt = (int*)alloc(kN * sizeof(int));
  int* csr_src = (int*)alloc((size_t)kN * kCap * sizeof(int));

  weight_prep_kernel<<<75, 256, 0, stream>>>(Wg, bp, cw, cb, Wgt, biasp, cnt);

  gemm_h_csr_mfma<<<1009, 256, 0, stream>>>(x, Wgt, asrc, adst, ei, cnt, csr_src,
                                            Wp, cw, Wqt, hb, sv, tv);

  gat_aggregate_kernel<<<kN, 256, 0, stream>>>(hb, sv, tv, bg, cnt, csr_src, hrelb);

  gemm_fused_mfma<<<640, 256, 0, stream>>>(hrelb, Wqt, biasp, out);
}

// Round 15
// 113.962 us; speedup vs baseline: 1.1098x; 1.0037x over previous
//
#include <hip/hip_runtime.h>
#include <hip/hip_bf16.h>
#include <hip/hip_fp16.h>
#include <cstdint>
#include <cstddef>

constexpr int kN = 10000;   // nodes
constexpr int kE = 320000;  // edges
constexpr int kM = 4;       // modalities
constexpr int kD = 256;     // feature dim
constexpr int kP = 256;     // pro dim
constexpr float kSlope = 0.2f;
constexpr int kCap = 96;    // CSR capacity/node: deg ~ Poisson(32), 96 = +11 sigma

typedef __attribute__((ext_vector_type(8))) short bf16x8;
typedef __attribute__((ext_vector_type(4))) float f32x4;
typedef __attribute__((ext_vector_type(2))) float f32x2;

__device__ __forceinline__ unsigned short f2bf(float f) {
  union { float ff; unsigned int i; } v; v.ff = f;
  unsigned int x = v.i;
  unsigned int r = x + 0x7fffu + ((x >> 16) & 1u);
  return (unsigned short)(r >> 16);
}
__device__ __forceinline__ uint4 pack8(float4 a, float4 b) {
  uint4 o;
  o.x = (unsigned)f2bf(a.x) | ((unsigned)f2bf(a.y) << 16);
  o.y = (unsigned)f2bf(a.z) | ((unsigned)f2bf(a.w) << 16);
  o.z = (unsigned)f2bf(b.x) | ((unsigned)f2bf(b.y) << 16);
  o.w = (unsigned)f2bf(b.z) | ((unsigned)f2bf(b.w) << 16);
  return o;
}
__device__ __forceinline__ void gload_lds16(const void* g, void* l) {
  __builtin_amdgcn_global_load_lds((const __attribute__((address_space(1))) unsigned int*)g,
                                   (__attribute__((address_space(3))) unsigned int*)l, 16, 0, 0);
}

// ---------------- weight prep (critical-path only): Wgt + biasp + cnt ----------

__global__ __launch_bounds__(256) void weight_prep_kernel(
    const float* __restrict__ Wg, const float* __restrict__ bp,
    const float* __restrict__ cw, const float* __restrict__ cb,
    unsigned short* __restrict__ Wgt, float* __restrict__ biasp, int* __restrict__ cnt) {
  const int blk = blockIdx.x;
  if (blk >= 65) {
    int z = blk - 65;
    int t = threadIdx.x;
    if (t < 250) ((int4*)cnt)[z * 250 + t] = make_int4(0, 0, 0, 0);
    return;
  }
  if (blk == 64) {
    int p = threadIdx.x;
    float v = cb[0];
#pragma unroll
    for (int mm = 0; mm < kM; mm++) v += cw[mm] * bp[mm * kP + p];
    biasp[p] = v;
    return;
  }
  __shared__ float tile[64][65];
  const int m = blk >> 4;
  const int t2 = blk & 15;
  const int r0 = (t2 >> 2) * 64;
  const int c0 = (t2 & 3) * 64;
  const float* in = Wg + ((size_t)m << 16);
#pragma unroll
  for (int l = 0; l < 16; l++) {
    int idx = l * 256 + threadIdx.x;
    int rr = idx >> 6, cc = idx & 63;
    tile[rr][cc] = in[(size_t)(c0 + rr) * 256 + r0 + cc];
  }
  __syncthreads();
#pragma unroll
  for (int l = 0; l < 16; l++) {
    int idx = l * 256 + threadIdx.x;
    int rr = idx >> 6, cc = idx & 63;
    Wgt[((size_t)m << 16) + (size_t)(r0 + rr) * 256 + c0 + cc] = f2bf(tile[cc][rr]);
  }
}

// ---------------- GEMM 1 (MFMA + full LDS staging, 2-phase dbuf) + CSR + Wqt ----
// blocks [0,632):    hb(fp16) = x @ Wg, fused s,t epilogue (m -> XCD pair {2m,2m+1})
// blocks [632,945):  capacity-CSR edge fill
// blocks [945,1009): Wqt transpose (consumed only by gemm_fused)

constexpr int ASTR = 64 * 8 + 8;    // A slot stride (elements)
constexpr int BSTR = 256 * 8 + 8;   // B slot stride (elements)
constexpr int kAsBytes = 2 * 4 * ASTR * 2;
constexpr int kBsBytes = 2 * 4 * BSTR * 2;

__global__ __launch_bounds__(256) void gemm_h_csr_mfma(
    const float* __restrict__ x, const unsigned short* __restrict__ Wgt,
    const float* __restrict__ asrc, const float* __restrict__ adst,
    const int* __restrict__ ei, int* __restrict__ cnt, int* __restrict__ csr_src,
    const float* __restrict__ Wp, const float* __restrict__ cw,
    unsigned short* __restrict__ Wqt,
    unsigned short* __restrict__ hb, float* __restrict__ sv, float* __restrict__ tv) {
  const int blk = blockIdx.x;
  const int tid = threadIdx.x;

  __shared__ __align__(16) char smem[kAsBytes + kBsBytes];
  __shared__ float sred[256], tred[256];
  auto As = (unsigned short(*)[4 * ASTR])smem;
  auto Bs = (unsigned short(*)[4 * BSTR])(smem + kAsBytes);

  if (blk >= 945) {
    auto tile = (float(*)[65])smem;
    const int b = blk - 945;
    const int m = b >> 4;
    const int t2 = b & 15;
    const int r0 = (t2 >> 2) * 64;
    const int c0 = (t2 & 3) * 64;
    const float* in = Wp + ((size_t)m << 16);
    const float scale = cw[m];
#pragma unroll
    for (int l = 0; l < 16; l++) {
      int idx = l * 256 + tid;
      int rr = idx >> 6, cc = idx & 63;
      tile[rr][cc] = in[(size_t)(c0 + rr) * 256 + r0 + cc] * scale;
    }
    __syncthreads();
#pragma unroll
    for (int l = 0; l < 16; l++) {
      int idx = l * 256 + tid;
      int rr = idx >> 6, cc = idx & 63;
      Wqt[(size_t)(r0 + rr) * 1024 + (m << 8) + c0 + cc] = f2bf(tile[cc][rr]);
    }
    return;
  }

  if (blk >= 632) {
    int t = (blk - 632) * 256 + tid;
    int e4 = t * 4;
    if (e4 >= kE) return;
    int4 s4 = *(const int4*)&ei[e4];
    int4 d4 = *(const int4*)&ei[kE + e4];
    int sl;
    sl = atomicAdd(&cnt[d4.x], 1); csr_src[d4.x * kCap + sl] = s4.x;
    sl = atomicAdd(&cnt[d4.y], 1); csr_src[d4.y * kCap + sl] = s4.y;
    sl = atomicAdd(&cnt[d4.z], 1); csr_src[d4.z * kCap + sl] = s4.z;
    sl = atomicAdd(&cnt[d4.w], 1); csr_src[d4.w * kCap + sl] = s4.w;
    return;
  }

  // m -> XCD pair {2m, 2m+1}
  const int m = (blk & 7) >> 1;
  const int i = (blk >> 3) * 2 + (blk & 1);
  if (i >= 157) return;
  const int row0 = i * 64;

  const int wave = tid >> 6, lane = tid & 63;
  const int lidx = lane & 15, lslot = lane >> 4;
  const int wcol0 = wave * 64;

  const int arow_s = tid & 63, aslot_s = tid >> 6;
  const int agr = min(row0 + arow_s, kN - 1);
  const float* Abase = x + ((size_t)m * kN + agr) * kD + aslot_s * 8;
  const unsigned short* Bbase = Wgt + (size_t)m * kD * kD;

  f32x4 acc[4][4] = {};

  {
    float4 f0 = *(const float4*)(Abase);
    float4 f1 = *(const float4*)(Abase + 4);
    *(uint4*)&As[0][aslot_s * ASTR + arow_s * 8] = pack8(f0, f1);
#pragma unroll
    for (int l = 0; l < 4; l++) {
      int c = tid + l * 256;
      int col = c & 255, slot = c >> 8;
      gload_lds16(Bbase + (size_t)col * kD + slot * 8, &Bs[0][slot * BSTR + col * 8]);
    }
  }
  __syncthreads();

  int buf = 0;
  for (int t = 0; t < 8; t++) {
    float4 f0, f1;
    const bool pf = (t < 7);
    if (pf) {
      const int k1 = (t + 1) * 32;
      f0 = *(const float4*)(Abase + k1);
      f1 = *(const float4*)(Abase + k1 + 4);
#pragma unroll
      for (int l = 0; l < 4; l++) {
        int c = tid + l * 256;
        int col = c & 255, slot = c >> 8;
        gload_lds16(Bbase + (size_t)col * kD + k1 + slot * 8,
                    &Bs[buf ^ 1][slot * BSTR + col * 8]);
      }
    }
    bf16x8 a[4], bfr[4];
#pragma unroll
    for (int i2 = 0; i2 < 4; i2++)
      a[i2] = *(const bf16x8*)&As[buf][lslot * ASTR + (i2 * 16 + lidx) * 8];
#pragma unroll
    for (int j = 0; j < 4; j++)
      bfr[j] = *(const bf16x8*)&Bs[buf][lslot * BSTR + (wcol0 + j * 16 + lidx) * 8];
#pragma unroll
    for (int i2 = 0; i2 < 4; i2++)
#pragma unroll
      for (int j = 0; j < 4; j++)
        acc[i2][j] = __builtin_amdgcn_mfma_f32_16x16x32_bf16(a[i2], bfr[j], acc[i2][j], 0, 0, 0);
    if (pf) {
      *(uint4*)&As[buf ^ 1][aslot_s * ASTR + arow_s * 8] = pack8(f0, f1);
    }
    __syncthreads();
    buf ^= 1;
  }

  // epilogue: store hb (fp16! only gat consumes it) + fused s,t dot products
  const int slot4 = lane >> 4;
  float av[4], dv[4];
#pragma unroll
  for (int j = 0; j < 4; j++) {
    av[j] = asrc[m * kD + wcol0 + j * 16 + lidx];
    dv[j] = adst[m * kD + wcol0 + j * 16 + lidx];
  }
#pragma unroll
  for (int i2 = 0; i2 < 4; i2++) {
#pragma unroll
    for (int reg = 0; reg < 4; reg++) {
      int grow = row0 + i2 * 16 + slot4 * 4 + reg;
      float sp = 0.f, tp = 0.f;
#pragma unroll
      for (int j = 0; j < 4; j++) {
        float hv = acc[i2][j][reg];
        sp += hv * av[j];
        tp += hv * dv[j];
        if (grow < kN)
          hb[((size_t)m * kN + grow) * kD + wcol0 + j * 16 + lidx] =
              __half_as_ushort(__float2half(hv));
      }
#pragma unroll
      for (int o = 1; o < 16; o <<= 1) {
        sp += __shfl_xor(sp, o);
        tp += __shfl_xor(tp, o);
      }
      if (lidx == 0) {
        sred[wave * 64 + i2 * 16 + slot4 * 4 + reg] = sp;
        tred[wave * 64 + i2 * 16 + slot4 * 4 + reg] = tp;
      }
    }
  }
  __syncthreads();
  if (tid < 64) {
    int grow = row0 + tid;
    if (grow < kN) {
      float s = sred[tid] + sred[64 + tid] + sred[128 + tid] + sred[192 + tid];
      float t = tred[tid] + tred[64 + tid] + tred[128 + tid] + tred[192 + tid];
      sv[m * kN + grow] = s;
      tv[m * kN + grow] = t;
    }
  }
}

// ---------------- GAT softmax + aggregate (capacity CSR, fp16 h) ----------------
// Wave per (m,n); modality->XCD affinity; edges in pairs (half-wave x 16B).
// LDS edge buffer {half2(ee,ee), src<<9}; gathers = SGPR base + 32b voffset.
// Inner loop: 4x v_pk_fma_f16 per edge -- ZERO unpack ops (fp16 h storage).
// Accumulate packed f16 (|acc| <= denom*max|h| ~ 7e3 << 65504; err ~6e-4),
// convert to f32 once at the end. Denominator stays f32.

__global__ __launch_bounds__(256) void gat_aggregate_kernel(
    const unsigned short* __restrict__ hb, const float* __restrict__ sv,
    const float* __restrict__ tv, const float* __restrict__ bg,
    const int* __restrict__ cnt, const int* __restrict__ csr_src,
    unsigned short* __restrict__ hrelb) {
  const int l = blockIdx.x;
  const int xcd = l & 7;
  const int m = xcd >> 1;
  const int ngroup = (l >> 3) * 2 + (xcd & 1);   // [0, 2500)
  const int wv = threadIdx.x >> 6;
  const int n = ngroup * 4 + wv;
  const int lane = threadIdx.x & 63;
  const int half = lane >> 5;
  const int lf = lane & 31;
  const int fb = lf * 8;                      // feature offset in elems (output)
  const unsigned fbyte = (unsigned)lf * 16u;  // feature offset in bytes

  __shared__ uint2 ebuf[4][64];               // {half2(ee,ee) bits, src*512}

  const float tt = tv[m * kN + n];
  const int b = n * kCap;
  const int deg = cnt[n];

  float a_self = sv[m * kN + n] + tt;
  a_self = fmaxf(a_self, kSlope * a_self);
  const float e_self = __expf(a_self);

  const char* hmB = (const char*)(hb + ((size_t)m * kN << 8));  // wave-uniform

  __half2 cacc[4];
  cacc[0] = cacc[1] = cacc[2] = cacc[3] = __float2half2_rn(0.f);
  {
    const __half2 es2 = __float2half2_rn(half ? 0.f : e_self);
    uint4 hx = *(const uint4*)(hmB + (((unsigned)n << 9) + fbyte));
#pragma unroll
    for (int q = 0; q < 4; q++) {
      unsigned w = ((const unsigned*)&hx)[q];
      __half2 hv2 = *reinterpret_cast<const __half2*>(&w);
      cacc[q] = __hfma2(hv2, es2, cacc[q]);
    }
  }
  float denom = (lane == 0) ? e_self : 0.f;

  for (int c0 = 0; c0 < deg; c0 += 64) {
    int j = c0 + lane;
    float ee = 0.f;
    unsigned soff = 0;
    if (j < deg) {
      int src = csr_src[b + j];
      float a = sv[m * kN + src] + tt;
      a = fmaxf(a, kSlope * a);
      ee = __expf(a);
      soff = (unsigned)src << 9;              // byte offset of source row
    }
    denom += ee;
    union { __half2 h2; unsigned u; } ec;
    ec.h2 = __float2half2_rn(ee);
    ebuf[wv][lane] = make_uint2(ec.u, soff);
    // same-wave LDS RAW: compiler inserts lgkmcnt wait, no barrier needed
    const int cl = min(64, deg - c0);
    const uint2* ebase = &ebuf[wv][half];     // half 0 -> even edge, 1 -> odd
    for (int j2 = 0; j2 < cl; j2 += 8) {
#pragma unroll
      for (int p = 0; p < 4; p++) {
        uint2 es_ = ebase[j2 + 2 * p];        // ds_read_b64, imm offset
        __half2 ep2 = *reinterpret_cast<const __half2*>(&es_.x);
        uint4 hx = *(const uint4*)(hmB + (es_.y + fbyte));
#pragma unroll
        for (int q = 0; q < 4; q++) {
          unsigned w = ((const unsigned*)&hx)[q];
          __half2 hv2 = *reinterpret_cast<const __half2*>(&w);
          cacc[q] = __hfma2(hv2, ep2, cacc[q]);
        }
      }
    }
  }
#pragma unroll
  for (int o = 32; o > 0; o >>= 1) denom += __shfl_xor(denom, o);
  const float inv = 1.f / (denom + 1e-16f);

  // f16 -> f32 once, then merge halves (lane L + L^32 share features)
  f32x2 acc2[4];
#pragma unroll
  for (int q = 0; q < 4; q++) {
    float2 f = __half22float2(cacc[q]);
    acc2[q].x = f.x + __shfl_xor(f.x, 32);
    acc2[q].y = f.y + __shfl_xor(f.y, 32);
  }

  if (half == 0) {
    const float* bgp = bg + m * kD + fb;
    float4 b0 = *(const float4*)bgp;
    float4 b1 = *(const float4*)(bgp + 4);
    float4 o0, o1;
    o0.x = fmaxf(acc2[0].x * inv + b0.x, 0.f);
    o0.y = fmaxf(acc2[0].y * inv + b0.y, 0.f);
    o0.z = fmaxf(acc2[1].x * inv + b0.z, 0.f);
    o0.w = fmaxf(acc2[1].y * inv + b0.w, 0.f);
    o1.x = fmaxf(acc2[2].x * inv + b1.x, 0.f);
    o1.y = fmaxf(acc2[2].y * inv + b1.y, 0.f);
    o1.z = fmaxf(acc2[3].x * inv + b1.z, 0.f);
    o1.w = fmaxf(acc2[3].y * inv + b1.w, 0.f);
    *(uint4*)(hrelb + (((size_t)m * kN + n) << 8) + fb) = pack8(o0, o1);
  }
}

// ---------------- GEMM 2 (MFMA + full LDS staging, 2-phase dbuf) ----------------

constexpr int FSTR = 64 * 8 + 8;

__global__ __launch_bounds__(256) void gemm_fused_mfma(const unsigned short* __restrict__ hrelb,
                                                       const unsigned short* __restrict__ Wqt,
                                                       const float* __restrict__ biasp,
                                                       float* __restrict__ out) {
  const int l = blockIdx.x;
  const int xcd = l & 7;
  const int t0 = l >> 3;
  const int c = t0 & 3;
  const int r = (t0 >> 2) * 8 + xcd;
  if (r >= 157) return;
  const int row0 = r * 64;
  const int col0 = c * 64;

  const int tid = threadIdx.x;
  const int wave = tid >> 6, lane = tid & 63;
  const int lidx = lane & 15, lslot = lane >> 4;
  const int wr = wave >> 1, wc = wave & 1;

  __shared__ __align__(16) unsigned short As[2][8 * FSTR];
  __shared__ __align__(16) unsigned short Bs[2][8 * FSTR];

  f32x4 acc[2][2] = {};

  const int arow = min(row0 + (tid & 63), kN - 1);
  const int bcol = col0 + (tid & 63);

#pragma unroll
  for (int ll = 0; ll < 2; ll++) {
    int slot = (tid >> 6) + ll * 4;
    gload_lds16(hrelb + ((size_t)arow << 8) + slot * 8,
                &As[0][slot * FSTR + (tid & 63) * 8]);
    gload_lds16(Wqt + (size_t)bcol * 1024 + slot * 8,
                &Bs[0][slot * FSTR + (tid & 63) * 8]);
  }
  __syncthreads();

  int buf = 0;
  for (int t = 0; t < 16; t++) {
    if (t < 15) {
      const int k1 = (t + 1) * 64;
      const int mm = k1 >> 8;
      const int d1 = k1 & 255;
#pragma unroll
      for (int ll = 0; ll < 2; ll++) {
        int slot = (tid >> 6) + ll * 4;
        gload_lds16(hrelb + (((size_t)mm * kN + arow) << 8) + d1 + slot * 8,
                    &As[buf ^ 1][slot * FSTR + (tid & 63) * 8]);
        gload_lds16(Wqt + (size_t)bcol * 1024 + k1 + slot * 8,
                    &Bs[buf ^ 1][slot * FSTR + (tid & 63) * 8]);
      }
    }
#pragma unroll
    for (int s = 0; s < 2; s++) {
      const int ks = s * 4 + lslot;
      bf16x8 a[2], bfr[2];
#pragma unroll
      for (int i = 0; i < 2; i++)
        a[i] = *(const bf16x8*)&As[buf][ks * FSTR + (wr * 32 + i * 16 + lidx) * 8];
#pragma unroll
      for (int j = 0; j < 2; j++)
        bfr[j] = *(const bf16x8*)&Bs[buf][ks * FSTR + (wc * 32 + j * 16 + lidx) * 8];
#pragma unroll
      for (int i = 0; i < 2; i++)
#pragma unroll
        for (int j = 0; j < 2; j++)
          acc[i][j] = __builtin_amdgcn_mfma_f32_16x16x32_bf16(a[i], bfr[j], acc[i][j], 0, 0, 0);
    }
    __syncthreads();
    buf ^= 1;
  }

  const int slot4 = lane >> 4;
#pragma unroll
  for (int i = 0; i < 2; i++) {
#pragma unroll
    for (int reg = 0; reg < 4; reg++) {
      int grow = row0 + wr * 32 + i * 16 + slot4 * 4 + reg;
      if (grow < kN) {
#pragma unroll
        for (int j = 0; j < 2; j++) {
          int gcol = col0 + wc * 32 + j * 16 + lidx;
          out[(size_t)grow * kP + gcol] = acc[i][j][reg] + biasp[gcol];
        }
      }
    }
  }
}

// ---------------- host launch ----------------

extern "C" void kernel_launch(void* const* d_in, const int* in_sizes, int n_in,
                              void* d_out, int out_size, void* d_ws, size_t ws_size,
                              hipStream_t stream) {
  const float* x = (const float*)d_in[0];
  const int* ei = (const int*)d_in[1];
  const float* Wg = (const float*)d_in[2];
  const float* asrc = (const float*)d_in[3];
  const float* adst = (const float*)d_in[4];
  const float* bg = (const float*)d_in[5];
  const float* Wp = (const float*)d_in[6];
  const float* bp = (const float*)d_in[7];
  const float* cw = (const float*)d_in[8];
  const float* cb = (const float*)d_in[9];
  float* out = (float*)d_out;

  char* ws = (char*)d_ws;
  size_t off = 0;
  auto alloc = [&](size_t bytes) -> void* {
    void* p = ws + off;
    off = (off + bytes + 255) & ~(size_t)255;
    return p;
  };
  unsigned short* hb = (unsigned short*)alloc((size_t)kM * kN * kD * 2);     // fp16
  unsigned short* hrelb = (unsigned short*)alloc((size_t)kM * kN * kD * 2);  // bf16
  unsigned short* Wgt = (unsigned short*)alloc((size_t)kM * kD * kD * 2);
  unsigned short* Wqt = (unsigned short*)alloc((size_t)kP * kM * kD * 2);
  float* sv = (float*)alloc((size_t)kM * kN * sizeof(float));
  float* tv = (float*)alloc((size_t)kM * kN * sizeof(float));
  float* biasp = (float*)alloc(kP * sizeof(float));
  int* cnt = (int*)alloc(kN * sizeof(int));
  int* csr_src = (int*)alloc((size_t)kN * kCap * sizeof(int));

  weight_prep_kernel<<<75, 256, 0, stream>>>(Wg, bp, cw, cb, Wgt, biasp, cnt);

  gemm_h_csr_mfma<<<1009, 256, 0, stream>>>(x, Wgt, asrc, adst, ei, cnt, csr_src,
                                            Wp, cw, Wqt, hb, sv, tv);

  gat_aggregate_kernel<<<kN, 256, 0, stream>>>(hb, sv, tv, bg, cnt, csr_src, hrelb);

  gemm_fused_mfma<<<640, 256, 0, stream>>>(hrelb, Wqt, biasp, out);
}

// Round 16
// 102.162 us; speedup vs baseline: 1.2380x; 1.1155x over previous
//
#include <hip/hip_runtime.h>
#include <hip/hip_bf16.h>
#include <hip/hip_fp16.h>
#include <cstdint>
#include <cstddef>

constexpr int kN = 10000;   // nodes
constexpr int kE = 320000;  // edges
constexpr int kM = 4;       // modalities
constexpr int kD = 256;     // feature dim
constexpr int kP = 256;     // pro dim
constexpr float kSlope = 0.2f;
constexpr int kCap = 96;    // CSR capacity/node: deg ~ Poisson(32), 96 = +11 sigma

// Tiled weight layouts (k-slot-major, = LDS layout, so gload_lds reads are
// lane-contiguous -- fixes the 64-transactions-per-wave column-slab reads):
//   Wgt_t[(m<<16) + (k>>3)*2048 + j*8 + (k&7)]   (j = output col, k = contraction)
//   Wqt_t[(q>>3)*2048 + p*8 + (q&7)]             (p = out col, q = m*256+d)
//   hrelb_t[((m*32 + (d>>3))*kN + n)*8 + (d&7)]  (gemm_fused A operand)

typedef __attribute__((ext_vector_type(8))) short bf16x8;
typedef __attribute__((ext_vector_type(4))) float f32x4;
typedef __attribute__((ext_vector_type(2))) float f32x2;

__device__ __forceinline__ unsigned short f2bf(float f) {
  union { float ff; unsigned int i; } v; v.ff = f;
  unsigned int x = v.i;
  unsigned int r = x + 0x7fffu + ((x >> 16) & 1u);
  return (unsigned short)(r >> 16);
}
__device__ __forceinline__ uint4 pack8(float4 a, float4 b) {
  uint4 o;
  o.x = (unsigned)f2bf(a.x) | ((unsigned)f2bf(a.y) << 16);
  o.y = (unsigned)f2bf(a.z) | ((unsigned)f2bf(a.w) << 16);
  o.z = (unsigned)f2bf(b.x) | ((unsigned)f2bf(b.y) << 16);
  o.w = (unsigned)f2bf(b.z) | ((unsigned)f2bf(b.w) << 16);
  return o;
}
__device__ __forceinline__ void gload_lds16(const void* g, void* l) {
  __builtin_amdgcn_global_load_lds((const __attribute__((address_space(1))) unsigned int*)g,
                                   (__attribute__((address_space(3))) unsigned int*)l, 16, 0, 0);
}

// ---------------- weight prep (critical-path only): Wgt_t + biasp + cnt ----------

__global__ __launch_bounds__(256) void weight_prep_kernel(
    const float* __restrict__ Wg, const float* __restrict__ bp,
    const float* __restrict__ cw, const float* __restrict__ cb,
    unsigned short* __restrict__ Wgt, float* __restrict__ biasp, int* __restrict__ cnt) {
  const int blk = blockIdx.x;
  if (blk >= 65) {
    int z = blk - 65;
    int t = threadIdx.x;
    if (t < 250) ((int4*)cnt)[z * 250 + t] = make_int4(0, 0, 0, 0);
    return;
  }
  if (blk == 64) {
    int p = threadIdx.x;
    float v = cb[0];
#pragma unroll
    for (int mm = 0; mm < kM; mm++) v += cw[mm] * bp[mm * kP + p];
    biasp[p] = v;
    return;
  }
  __shared__ float tile[64][65];
  const int m = blk >> 4;
  const int t2 = blk & 15;
  const int r0 = (t2 >> 2) * 64;
  const int c0 = (t2 & 3) * 64;
  const float* in = Wg + ((size_t)m << 16);
#pragma unroll
  for (int l = 0; l < 16; l++) {
    int idx = l * 256 + threadIdx.x;
    int rr = idx >> 6, cc = idx & 63;
    tile[rr][cc] = in[(size_t)(c0 + rr) * 256 + r0 + cc];
  }
  __syncthreads();
#pragma unroll
  for (int l = 0; l < 16; l++) {
    int idx = l * 256 + threadIdx.x;
    int rr = idx >> 6, cc = idx & 63;
    int j = r0 + rr, k = c0 + cc;   // value = Wg[m][k][j]
    Wgt[((size_t)m << 16) + ((k >> 3) << 11) + j * 8 + (k & 7)] = f2bf(tile[cc][rr]);
  }
}

// ---------------- GEMM 1 (MFMA + LDS dbuf, tiled-B) + CSR fill + Wqt prep -------
// blocks [0,632):    hb(fp16) = x @ Wg, fused s,t epilogue (m -> XCD pair {2m,2m+1})
// blocks [632,945):  capacity-CSR edge fill
// blocks [945,1009): Wqt_t transpose (consumed only by gemm_fused)

constexpr int ASTR = 64 * 8 + 8;    // A slot stride (elements)
constexpr int BSTR = 256 * 8 + 8;   // B slot stride (elements)
constexpr int kAsBytes = 2 * 4 * ASTR * 2;
constexpr int kBsBytes = 2 * 4 * BSTR * 2;

__global__ __launch_bounds__(256) void gemm_h_csr_mfma(
    const float* __restrict__ x, const unsigned short* __restrict__ Wgt,
    const float* __restrict__ asrc, const float* __restrict__ adst,
    const int* __restrict__ ei, int* __restrict__ cnt, int* __restrict__ csr_src,
    const float* __restrict__ Wp, const float* __restrict__ cw,
    unsigned short* __restrict__ Wqt,
    unsigned short* __restrict__ hb, float* __restrict__ sv, float* __restrict__ tv) {
  const int blk = blockIdx.x;
  const int tid = threadIdx.x;

  __shared__ __align__(16) char smem[kAsBytes + kBsBytes];
  __shared__ float sred[256], tred[256];
  auto As = (unsigned short(*)[4 * ASTR])smem;
  auto Bs = (unsigned short(*)[4 * BSTR])(smem + kAsBytes);

  if (blk >= 945) {
    auto tile = (float(*)[65])smem;
    const int b = blk - 945;
    const int m = b >> 4;
    const int t2 = b & 15;
    const int r0 = (t2 >> 2) * 64;
    const int c0 = (t2 & 3) * 64;
    const float* in = Wp + ((size_t)m << 16);
    const float scale = cw[m];
#pragma unroll
    for (int l = 0; l < 16; l++) {
      int idx = l * 256 + tid;
      int rr = idx >> 6, cc = idx & 63;
      tile[rr][cc] = in[(size_t)(c0 + rr) * 256 + r0 + cc] * scale;
    }
    __syncthreads();
#pragma unroll
    for (int l = 0; l < 16; l++) {
      int idx = l * 256 + tid;
      int rr = idx >> 6, cc = idx & 63;
      int p = r0 + rr;
      int q = (m << 8) + c0 + cc;    // value = cw[m]*Wp[m][d=c0+cc][p]
      Wqt[((q >> 3) << 11) + p * 8 + (q & 7)] = f2bf(tile[cc][rr]);
    }
    return;
  }

  if (blk >= 632) {
    int t = (blk - 632) * 256 + tid;
    int e4 = t * 4;
    if (e4 >= kE) return;
    int4 s4 = *(const int4*)&ei[e4];
    int4 d4 = *(const int4*)&ei[kE + e4];
    int sl;
    sl = atomicAdd(&cnt[d4.x], 1); csr_src[d4.x * kCap + sl] = s4.x;
    sl = atomicAdd(&cnt[d4.y], 1); csr_src[d4.y * kCap + sl] = s4.y;
    sl = atomicAdd(&cnt[d4.z], 1); csr_src[d4.z * kCap + sl] = s4.z;
    sl = atomicAdd(&cnt[d4.w], 1); csr_src[d4.w * kCap + sl] = s4.w;
    return;
  }

  // m -> XCD pair {2m, 2m+1}
  const int m = (blk & 7) >> 1;
  const int i = (blk >> 3) * 2 + (blk & 1);
  if (i >= 157) return;
  const int row0 = i * 64;

  const int wave = tid >> 6, lane = tid & 63;
  const int lidx = lane & 15, lslot = lane >> 4;
  const int wcol0 = wave * 64;

  // A staging: 4 threads/row (128-B contiguous runs), 64 rows x 4 slots
  const int arow_s = tid >> 2, aslot_s = tid & 3;
  const int agr = min(row0 + arow_s, kN - 1);
  const float* Abase = x + ((size_t)m * kN + agr) * kD + aslot_s * 8;
  const unsigned short* Bbase = Wgt + ((size_t)m << 16);

  f32x4 acc[4][4] = {};

  {
    float4 f0 = *(const float4*)(Abase);
    float4 f1 = *(const float4*)(Abase + 4);
    *(uint4*)&As[0][aslot_s * ASTR + arow_s * 8] = pack8(f0, f1);
    // B tile 0: slots 0..3, lane-contiguous tiled reads (1 KB/wave)
#pragma unroll
    for (int l = 0; l < 4; l++) {
      gload_lds16(Bbase + ((size_t)l << 11) + tid * 8, &Bs[0][l * BSTR + tid * 8]);
    }
  }
  __syncthreads();

  int buf = 0;
  for (int t = 0; t < 8; t++) {
    float4 f0, f1;
    const bool pf = (t < 7);
    if (pf) {
      const int k1 = (t + 1) * 32;
      f0 = *(const float4*)(Abase + k1);
      f1 = *(const float4*)(Abase + k1 + 4);
      const int kb1 = (t + 1) * 4;   // global k-slot base
#pragma unroll
      for (int l = 0; l < 4; l++) {
        gload_lds16(Bbase + ((size_t)(kb1 + l) << 11) + tid * 8,
                    &Bs[buf ^ 1][l * BSTR + tid * 8]);
      }
    }
    bf16x8 a[4], bfr[4];
#pragma unroll
    for (int i2 = 0; i2 < 4; i2++)
      a[i2] = *(const bf16x8*)&As[buf][lslot * ASTR + (i2 * 16 + lidx) * 8];
#pragma unroll
    for (int j = 0; j < 4; j++)
      bfr[j] = *(const bf16x8*)&Bs[buf][lslot * BSTR + (wcol0 + j * 16 + lidx) * 8];
#pragma unroll
    for (int i2 = 0; i2 < 4; i2++)
#pragma unroll
      for (int j = 0; j < 4; j++)
        acc[i2][j] = __builtin_amdgcn_mfma_f32_16x16x32_bf16(a[i2], bfr[j], acc[i2][j], 0, 0, 0);
    if (pf) {
      *(uint4*)&As[buf ^ 1][aslot_s * ASTR + arow_s * 8] = pack8(f0, f1);
    }
    __syncthreads();
    buf ^= 1;
  }

  // epilogue: store hb (fp16, row-major -- gat's gather layout) + fused s,t
  const int slot4 = lane >> 4;
  float av[4], dv[4];
#pragma unroll
  for (int j = 0; j < 4; j++) {
    av[j] = asrc[m * kD + wcol0 + j * 16 + lidx];
    dv[j] = adst[m * kD + wcol0 + j * 16 + lidx];
  }
#pragma unroll
  for (int i2 = 0; i2 < 4; i2++) {
#pragma unroll
    for (int reg = 0; reg < 4; reg++) {
      int grow = row0 + i2 * 16 + slot4 * 4 + reg;
      float sp = 0.f, tp = 0.f;
#pragma unroll
      for (int j = 0; j < 4; j++) {
        float hv = acc[i2][j][reg];
        sp += hv * av[j];
        tp += hv * dv[j];
        if (grow < kN)
          hb[((size_t)m * kN + grow) * kD + wcol0 + j * 16 + lidx] =
              __half_as_ushort(__float2half(hv));
      }
#pragma unroll
      for (int o = 1; o < 16; o <<= 1) {
        sp += __shfl_xor(sp, o);
        tp += __shfl_xor(tp, o);
      }
      if (lidx == 0) {
        sred[wave * 64 + i2 * 16 + slot4 * 4 + reg] = sp;
        tred[wave * 64 + i2 * 16 + slot4 * 4 + reg] = tp;
      }
    }
  }
  __syncthreads();
  if (tid < 64) {
    int grow = row0 + tid;
    if (grow < kN) {
      float s = sred[tid] + sred[64 + tid] + sred[128 + tid] + sred[192 + tid];
      float t = tred[tid] + tred[64 + tid] + tred[128 + tid] + tred[192 + tid];
      sv[m * kN + grow] = s;
      tv[m * kN + grow] = t;
    }
  }
}

// ---------------- GAT softmax + aggregate (capacity CSR, fp16 h) ----------------
// Wave per (m,n); modality->XCD affinity; edges in pairs (half-wave x 16B).
// LDS edge buffer {half2(ee,ee), src<<9}; gathers = SGPR base + 32b voffset.
// Output hrelb in k-slot-tiled layout (gemm_fused's staging wants it).

__global__ __launch_bounds__(256) void gat_aggregate_kernel(
    const unsigned short* __restrict__ hb, const float* __restrict__ sv,
    const float* __restrict__ tv, const float* __restrict__ bg,
    const int* __restrict__ cnt, const int* __restrict__ csr_src,
    unsigned short* __restrict__ hrelb) {
  const int l = blockIdx.x;
  const int xcd = l & 7;
  const int m = xcd >> 1;
  const int ngroup = (l >> 3) * 2 + (xcd & 1);   // [0, 2500)
  const int wv = threadIdx.x >> 6;
  const int n = ngroup * 4 + wv;
  const int lane = threadIdx.x & 63;
  const int half = lane >> 5;
  const int lf = lane & 31;
  const int fb = lf * 8;                      // feature offset in elems
  const unsigned fbyte = (unsigned)lf * 16u;  // feature offset in bytes

  __shared__ uint2 ebuf[4][64];               // {half2(ee,ee) bits, src*512}

  const float tt = tv[m * kN + n];
  const int b = n * kCap;
  const int deg = cnt[n];

  float a_self = sv[m * kN + n] + tt;
  a_self = fmaxf(a_self, kSlope * a_self);
  const float e_self = __expf(a_self);

  const char* hmB = (const char*)(hb + ((size_t)m * kN << 8));  // wave-uniform

  __half2 cacc[4];
  cacc[0] = cacc[1] = cacc[2] = cacc[3] = __float2half2_rn(0.f);
  {
    const __half2 es2 = __float2half2_rn(half ? 0.f : e_self);
    uint4 hx = *(const uint4*)(hmB + (((unsigned)n << 9) + fbyte));
#pragma unroll
    for (int q = 0; q < 4; q++) {
      unsigned w = ((const unsigned*)&hx)[q];
      __half2 hv2 = *reinterpret_cast<const __half2*>(&w);
      cacc[q] = __hfma2(hv2, es2, cacc[q]);
    }
  }
  float denom = (lane == 0) ? e_self : 0.f;

  for (int c0 = 0; c0 < deg; c0 += 64) {
    int j = c0 + lane;
    float ee = 0.f;
    unsigned soff = 0;
    if (j < deg) {
      int src = csr_src[b + j];
      float a = sv[m * kN + src] + tt;
      a = fmaxf(a, kSlope * a);
      ee = __expf(a);
      soff = (unsigned)src << 9;
    }
    denom += ee;
    union { __half2 h2; unsigned u; } ec;
    ec.h2 = __float2half2_rn(ee);
    ebuf[wv][lane] = make_uint2(ec.u, soff);
    const int cl = min(64, deg - c0);
    const uint2* ebase = &ebuf[wv][half];
    for (int j2 = 0; j2 < cl; j2 += 8) {
#pragma unroll
      for (int p = 0; p < 4; p++) {
        uint2 es_ = ebase[j2 + 2 * p];
        __half2 ep2 = *reinterpret_cast<const __half2*>(&es_.x);
        uint4 hx = *(const uint4*)(hmB + (es_.y + fbyte));
#pragma unroll
        for (int q = 0; q < 4; q++) {
          unsigned w = ((const unsigned*)&hx)[q];
          __half2 hv2 = *reinterpret_cast<const __half2*>(&w);
          cacc[q] = __hfma2(hv2, ep2, cacc[q]);
        }
      }
    }
  }
#pragma unroll
  for (int o = 32; o > 0; o >>= 1) denom += __shfl_xor(denom, o);
  const float inv = 1.f / (denom + 1e-16f);

  f32x2 acc2[4];
#pragma unroll
  for (int q = 0; q < 4; q++) {
    float2 f = __half22float2(cacc[q]);
    acc2[q].x = f.x + __shfl_xor(f.x, 32);
    acc2[q].y = f.y + __shfl_xor(f.y, 32);
  }

  if (half == 0) {
    const float* bgp = bg + m * kD + fb;
    float4 b0 = *(const float4*)bgp;
    float4 b1 = *(const float4*)(bgp + 4);
    float4 o0, o1;
    o0.x = fmaxf(acc2[0].x * inv + b0.x, 0.f);
    o0.y = fmaxf(acc2[0].y * inv + b0.y, 0.f);
    o0.z = fmaxf(acc2[1].x * inv + b0.z, 0.f);
    o0.w = fmaxf(acc2[1].y * inv + b0.w, 0.f);
    o1.x = fmaxf(acc2[2].x * inv + b1.x, 0.f);
    o1.y = fmaxf(acc2[2].y * inv + b1.y, 0.f);
    o1.z = fmaxf(acc2[3].x * inv + b1.z, 0.f);
    o1.w = fmaxf(acc2[3].y * inv + b1.w, 0.f);
    // tiled store: d-slot = lf, chunk = ((m*32+lf)*kN + n)*8
    *(uint4*)(hrelb + (((size_t)(m * 32 + lf)) * kN + n) * 8) = pack8(o0, o1);
  }
}

// ---------------- GEMM 2 (MFMA + LDS dbuf, tiled A and B) ----------------------
// out = hrel([N,1024] view) @ Wq + biasp; both operands k-slot-tiled so all
// gload_lds reads are lane-contiguous.

constexpr int FSTR = 64 * 8 + 8;

__global__ __launch_bounds__(256) void gemm_fused_mfma(const unsigned short* __restrict__ hrelb,
                                                       const unsigned short* __restrict__ Wqt,
                                                       const float* __restrict__ biasp,
                                                       float* __restrict__ out) {
  const int l = blockIdx.x;
  const int xcd = l & 7;
  const int t0 = l >> 3;
  const int c = t0 & 3;
  const int r = (t0 >> 2) * 8 + xcd;
  if (r >= 157) return;
  const int row0 = r * 64;
  const int col0 = c * 64;

  const int tid = threadIdx.x;
  const int wave = tid >> 6, lane = tid & 63;
  const int lidx = lane & 15, lslot = lane >> 4;
  const int wr = wave >> 1, wc = wave & 1;

  __shared__ __align__(16) unsigned short As[2][8 * FSTR];
  __shared__ __align__(16) unsigned short Bs[2][8 * FSTR];

  f32x4 acc[2][2] = {};

  const int arow = min(row0 + (tid & 63), kN - 1);
  const int bcol = col0 + (tid & 63);

  // stage K-tile 0 (k-slots 0..7)
#pragma unroll
  for (int ll = 0; ll < 2; ll++) {
    int slot = (tid >> 6) + ll * 4;
    gload_lds16(hrelb + ((size_t)slot * kN + arow) * 8,
                &As[0][slot * FSTR + (tid & 63) * 8]);
    gload_lds16(Wqt + ((size_t)slot << 11) + bcol * 8,
                &Bs[0][slot * FSTR + (tid & 63) * 8]);
  }
  __syncthreads();

  int buf = 0;
  for (int t = 0; t < 16; t++) {
    if (t < 15) {
      const int kb1 = (t + 1) * 8;   // global k-slot base
#pragma unroll
      for (int ll = 0; ll < 2; ll++) {
        int slot = (tid >> 6) + ll * 4;
        gload_lds16(hrelb + ((size_t)(kb1 + slot) * kN + arow) * 8,
                    &As[buf ^ 1][slot * FSTR + (tid & 63) * 8]);
        gload_lds16(Wqt + ((size_t)(kb1 + slot) << 11) + bcol * 8,
                    &Bs[buf ^ 1][slot * FSTR + (tid & 63) * 8]);
      }
    }
#pragma unroll
    for (int s = 0; s < 2; s++) {
      const int ks = s * 4 + lslot;
      bf16x8 a[2], bfr[2];
#pragma unroll
      for (int i = 0; i < 2; i++)
        a[i] = *(const bf16x8*)&As[buf][ks * FSTR + (wr * 32 + i * 16 + lidx) * 8];
#pragma unroll
      for (int j = 0; j < 2; j++)
        bfr[j] = *(const bf16x8*)&Bs[buf][ks * FSTR + (wc * 32 + j * 16 + lidx) * 8];
#pragma unroll
      for (int i = 0; i < 2; i++)
#pragma unroll
        for (int j = 0; j < 2; j++)
          acc[i][j] = __builtin_amdgcn_mfma_f32_16x16x32_bf16(a[i], bfr[j], acc[i][j], 0, 0, 0);
    }
    __syncthreads();
    buf ^= 1;
  }

  const int slot4 = lane >> 4;
#pragma unroll
  for (int i = 0; i < 2; i++) {
#pragma unroll
    for (int reg = 0; reg < 4; reg++) {
      int grow = row0 + wr * 32 + i * 16 + slot4 * 4 + reg;
      if (grow < kN) {
#pragma unroll
        for (int j = 0; j < 2; j++) {
          int gcol = col0 + wc * 32 + j * 16 + lidx;
          out[(size_t)grow * kP + gcol] = acc[i][j][reg] + biasp[gcol];
        }
      }
    }
  }
}

// ---------------- host launch ----------------

extern "C" void kernel_launch(void* const* d_in, const int* in_sizes, int n_in,
                              void* d_out, int out_size, void* d_ws, size_t ws_size,
                              hipStream_t stream) {
  const float* x = (const float*)d_in[0];
  const int* ei = (const int*)d_in[1];
  const float* Wg = (const float*)d_in[2];
  const float* asrc = (const float*)d_in[3];
  const float* adst = (const float*)d_in[4];
  const float* bg = (const float*)d_in[5];
  const float* Wp = (const float*)d_in[6];
  const float* bp = (const float*)d_in[7];
  const float* cw = (const float*)d_in[8];
  const float* cb = (const float*)d_in[9];
  float* out = (float*)d_out;

  char* ws = (char*)d_ws;
  size_t off = 0;
  auto alloc = [&](size_t bytes) -> void* {
    void* p = ws + off;
    off = (off + bytes + 255) & ~(size_t)255;
    return p;
  };
  unsigned short* hb = (unsigned short*)alloc((size_t)kM * kN * kD * 2);     // fp16 row-major
  unsigned short* hrelb = (unsigned short*)alloc((size_t)kM * kN * kD * 2);  // bf16 k-tiled
  unsigned short* Wgt = (unsigned short*)alloc((size_t)kM * kD * kD * 2);    // bf16 k-tiled
  unsigned short* Wqt = (unsigned short*)alloc((size_t)kP * kM * kD * 2);    // bf16 k-tiled
  float* sv = (float*)alloc((size_t)kM * kN * sizeof(float));
  float* tv = (float*)alloc((size_t)kM * kN * sizeof(float));
  float* biasp = (float*)alloc(kP * sizeof(float));
  int* cnt = (int*)alloc(kN * sizeof(int));
  int* csr_src = (int*)alloc((size_t)kN * kCap * sizeof(int));

  weight_prep_kernel<<<75, 256, 0, stream>>>(Wg, bp, cw, cb, Wgt, biasp, cnt);

  gemm_h_csr_mfma<<<1009, 256, 0, stream>>>(x, Wgt, asrc, adst, ei, cnt, csr_src,
                                            Wp, cw, Wqt, hb, sv, tv);

  gat_aggregate_kernel<<<kN, 256, 0, stream>>>(hb, sv, tv, bg, cnt, csr_src, hrelb);

  gemm_fused_mfma<<<640, 256, 0, stream>>>(hrelb, Wqt, biasp, out);
}

// Round 17
// 97.106 us; speedup vs baseline: 1.3025x; 1.0521x over previous
//
#include <hip/hip_runtime.h>
#include <hip/hip_bf16.h>
#include <hip/hip_fp16.h>
#include <cstdint>
#include <cstddef>

constexpr int kN = 10000;   // nodes
constexpr int kE = 320000;  // edges
constexpr int kM = 4;       // modalities
constexpr int kD = 256;     // feature dim
constexpr int kP = 256;     // pro dim
constexpr float kSlope = 0.2f;
constexpr int kCap = 96;    // CSR capacity/node: deg ~ Poisson(32), 96 = +11 sigma

// Tiled weight layouts (k-slot-major, = LDS layout, so gload_lds reads are
// lane-contiguous):
//   Wgt_t[(m<<16) + (k>>3)*2048 + j*8 + (k&7)]
//   Wqt_t[(q>>3)*2048 + p*8 + (q&7)]
//   hrelb_t[((m*32 + (d>>3))*kN + n)*8 + (d&7)]

typedef __attribute__((ext_vector_type(8))) short bf16x8;
typedef __attribute__((ext_vector_type(4))) float f32x4;
typedef __attribute__((ext_vector_type(2))) float f32x2;

__device__ __forceinline__ unsigned short f2bf(float f) {
  union { float ff; unsigned int i; } v; v.ff = f;
  unsigned int x = v.i;
  unsigned int r = x + 0x7fffu + ((x >> 16) & 1u);
  return (unsigned short)(r >> 16);
}
__device__ __forceinline__ uint4 pack8(float4 a, float4 b) {
  uint4 o;
  o.x = (unsigned)f2bf(a.x) | ((unsigned)f2bf(a.y) << 16);
  o.y = (unsigned)f2bf(a.z) | ((unsigned)f2bf(a.w) << 16);
  o.z = (unsigned)f2bf(b.x) | ((unsigned)f2bf(b.y) << 16);
  o.w = (unsigned)f2bf(b.z) | ((unsigned)f2bf(b.w) << 16);
  return o;
}
__device__ __forceinline__ void gload_lds16(const void* g, void* l) {
  __builtin_amdgcn_global_load_lds((const __attribute__((address_space(1))) unsigned int*)g,
                                   (__attribute__((address_space(3))) unsigned int*)l, 16, 0, 0);
}

// ---------------- weight prep (critical-path only): Wgt_t + biasp + cnt ----------

__global__ __launch_bounds__(256) void weight_prep_kernel(
    const float* __restrict__ Wg, const float* __restrict__ bp,
    const float* __restrict__ cw, const float* __restrict__ cb,
    unsigned short* __restrict__ Wgt, float* __restrict__ biasp, int* __restrict__ cnt) {
  const int blk = blockIdx.x;
  if (blk >= 65) {
    int z = blk - 65;
    int t = threadIdx.x;
    if (t < 250) ((int4*)cnt)[z * 250 + t] = make_int4(0, 0, 0, 0);
    return;
  }
  if (blk == 64) {
    int p = threadIdx.x;
    float v = cb[0];
#pragma unroll
    for (int mm = 0; mm < kM; mm++) v += cw[mm] * bp[mm * kP + p];
    biasp[p] = v;
    return;
  }
  __shared__ float tile[64][65];
  const int m = blk >> 4;
  const int t2 = blk & 15;
  const int r0 = (t2 >> 2) * 64;
  const int c0 = (t2 & 3) * 64;
  const float* in = Wg + ((size_t)m << 16);
#pragma unroll
  for (int l = 0; l < 16; l++) {
    int idx = l * 256 + threadIdx.x;
    int rr = idx >> 6, cc = idx & 63;
    tile[rr][cc] = in[(size_t)(c0 + rr) * 256 + r0 + cc];
  }
  __syncthreads();
#pragma unroll
  for (int l = 0; l < 16; l++) {
    int idx = l * 256 + threadIdx.x;
    int rr = idx >> 6, cc = idx & 63;
    int j = r0 + rr, k = c0 + cc;   // value = Wg[m][k][j]
    Wgt[((size_t)m << 16) + ((k >> 3) << 11) + j * 8 + (k & 7)] = f2bf(tile[cc][rr]);
  }
}

// ---------------- GEMM 1 (MFMA + LDS dbuf, tiled-B) + CSR fill + Wqt prep -------

constexpr int ASTR = 64 * 8 + 8;    // A slot stride (elements)
constexpr int BSTR = 256 * 8 + 8;   // B slot stride (elements)
constexpr int kAsBytes = 2 * 4 * ASTR * 2;
constexpr int kBsBytes = 2 * 4 * BSTR * 2;

__global__ __launch_bounds__(256) void gemm_h_csr_mfma(
    const float* __restrict__ x, const unsigned short* __restrict__ Wgt,
    const float* __restrict__ asrc, const float* __restrict__ adst,
    const int* __restrict__ ei, int* __restrict__ cnt, int* __restrict__ csr_src,
    const float* __restrict__ Wp, const float* __restrict__ cw,
    unsigned short* __restrict__ Wqt,
    unsigned short* __restrict__ hb, float* __restrict__ sv, float* __restrict__ tv) {
  const int blk = blockIdx.x;
  const int tid = threadIdx.x;

  __shared__ __align__(16) char smem[kAsBytes + kBsBytes];
  __shared__ float sred[256], tred[256];
  auto As = (unsigned short(*)[4 * ASTR])smem;
  auto Bs = (unsigned short(*)[4 * BSTR])(smem + kAsBytes);

  if (blk >= 945) {
    auto tile = (float(*)[65])smem;
    const int b = blk - 945;
    const int m = b >> 4;
    const int t2 = b & 15;
    const int r0 = (t2 >> 2) * 64;
    const int c0 = (t2 & 3) * 64;
    const float* in = Wp + ((size_t)m << 16);
    const float scale = cw[m];
#pragma unroll
    for (int l = 0; l < 16; l++) {
      int idx = l * 256 + tid;
      int rr = idx >> 6, cc = idx & 63;
      tile[rr][cc] = in[(size_t)(c0 + rr) * 256 + r0 + cc] * scale;
    }
    __syncthreads();
#pragma unroll
    for (int l = 0; l < 16; l++) {
      int idx = l * 256 + tid;
      int rr = idx >> 6, cc = idx & 63;
      int p = r0 + rr;
      int q = (m << 8) + c0 + cc;
      Wqt[((q >> 3) << 11) + p * 8 + (q & 7)] = f2bf(tile[cc][rr]);
    }
    return;
  }

  if (blk >= 632) {
    int t = (blk - 632) * 256 + tid;
    int e4 = t * 4;
    if (e4 >= kE) return;
    int4 s4 = *(const int4*)&ei[e4];
    int4 d4 = *(const int4*)&ei[kE + e4];
    int sl;
    sl = atomicAdd(&cnt[d4.x], 1); csr_src[d4.x * kCap + sl] = s4.x;
    sl = atomicAdd(&cnt[d4.y], 1); csr_src[d4.y * kCap + sl] = s4.y;
    sl = atomicAdd(&cnt[d4.z], 1); csr_src[d4.z * kCap + sl] = s4.z;
    sl = atomicAdd(&cnt[d4.w], 1); csr_src[d4.w * kCap + sl] = s4.w;
    return;
  }

  // m -> XCD pair {2m, 2m+1}
  const int m = (blk & 7) >> 1;
  const int i = (blk >> 3) * 2 + (blk & 1);
  if (i >= 157) return;
  const int row0 = i * 64;

  const int wave = tid >> 6, lane = tid & 63;
  const int lidx = lane & 15, lslot = lane >> 4;
  const int wcol0 = wave * 64;

  // A staging: 4 threads/row (128-B contiguous runs)
  const int arow_s = tid >> 2, aslot_s = tid & 3;
  const int agr = min(row0 + arow_s, kN - 1);
  const float* Abase = x + ((size_t)m * kN + agr) * kD + aslot_s * 8;
  const unsigned short* Bbase = Wgt + ((size_t)m << 16);

  f32x4 acc[4][4] = {};

  {
    float4 f0 = *(const float4*)(Abase);
    float4 f1 = *(const float4*)(Abase + 4);
    *(uint4*)&As[0][aslot_s * ASTR + arow_s * 8] = pack8(f0, f1);
#pragma unroll
    for (int l = 0; l < 4; l++) {
      gload_lds16(Bbase + ((size_t)l << 11) + tid * 8, &Bs[0][l * BSTR + tid * 8]);
    }
  }
  __syncthreads();

  int buf = 0;
  for (int t = 0; t < 8; t++) {
    float4 f0, f1;
    const bool pf = (t < 7);
    if (pf) {
      const int k1 = (t + 1) * 32;
      f0 = *(const float4*)(Abase + k1);
      f1 = *(const float4*)(Abase + k1 + 4);
      const int kb1 = (t + 1) * 4;
#pragma unroll
      for (int l = 0; l < 4; l++) {
        gload_lds16(Bbase + ((size_t)(kb1 + l) << 11) + tid * 8,
                    &Bs[buf ^ 1][l * BSTR + tid * 8]);
      }
    }
    bf16x8 a[4], bfr[4];
#pragma unroll
    for (int i2 = 0; i2 < 4; i2++)
      a[i2] = *(const bf16x8*)&As[buf][lslot * ASTR + (i2 * 16 + lidx) * 8];
#pragma unroll
    for (int j = 0; j < 4; j++)
      bfr[j] = *(const bf16x8*)&Bs[buf][lslot * BSTR + (wcol0 + j * 16 + lidx) * 8];
#pragma unroll
    for (int i2 = 0; i2 < 4; i2++)
#pragma unroll
      for (int j = 0; j < 4; j++)
        acc[i2][j] = __builtin_amdgcn_mfma_f32_16x16x32_bf16(a[i2], bfr[j], acc[i2][j], 0, 0, 0);
    if (pf) {
      *(uint4*)&As[buf ^ 1][aslot_s * ASTR + arow_s * 8] = pack8(f0, f1);
    }
    __syncthreads();
    buf ^= 1;
  }

  // epilogue: store hb (fp16 row-major) + fused s,t
  const int slot4 = lane >> 4;
  float av[4], dv[4];
#pragma unroll
  for (int j = 0; j < 4; j++) {
    av[j] = asrc[m * kD + wcol0 + j * 16 + lidx];
    dv[j] = adst[m * kD + wcol0 + j * 16 + lidx];
  }
#pragma unroll
  for (int i2 = 0; i2 < 4; i2++) {
#pragma unroll
    for (int reg = 0; reg < 4; reg++) {
      int grow = row0 + i2 * 16 + slot4 * 4 + reg;
      float sp = 0.f, tp = 0.f;
#pragma unroll
      for (int j = 0; j < 4; j++) {
        float hv = acc[i2][j][reg];
        sp += hv * av[j];
        tp += hv * dv[j];
        if (grow < kN)
          hb[((size_t)m * kN + grow) * kD + wcol0 + j * 16 + lidx] =
              __half_as_ushort(__float2half(hv));
      }
#pragma unroll
      for (int o = 1; o < 16; o <<= 1) {
        sp += __shfl_xor(sp, o);
        tp += __shfl_xor(tp, o);
      }
      if (lidx == 0) {
        sred[wave * 64 + i2 * 16 + slot4 * 4 + reg] = sp;
        tred[wave * 64 + i2 * 16 + slot4 * 4 + reg] = tp;
      }
    }
  }
  __syncthreads();
  if (tid < 64) {
    int grow = row0 + tid;
    if (grow < kN) {
      float s = sred[tid] + sred[64 + tid] + sred[128 + tid] + sred[192 + tid];
      float t = tred[tid] + tred[64 + tid] + tred[128 + tid] + tred[192 + tid];
      sv[m * kN + grow] = s;
      tv[m * kN + grow] = t;
    }
  }
}

// ---------------- GAT softmax + aggregate (capacity CSR, fp16 h) ----------------
// Wave per (m,n); modality->XCD affinity; edges in pairs (half-wave x 16B).
// LDS edge buffer {half2(ee,ee), src<<9}; gathers = SGPR base + 32b voffset.
// Output: block-level LDS transpose -> 64B full-line tiled stores (no RMW).

__global__ __launch_bounds__(256) void gat_aggregate_kernel(
    const unsigned short* __restrict__ hb, const float* __restrict__ sv,
    const float* __restrict__ tv, const float* __restrict__ bg,
    const int* __restrict__ cnt, const int* __restrict__ csr_src,
    unsigned short* __restrict__ hrelb) {
  const int l = blockIdx.x;
  const int xcd = l & 7;
  const int m = xcd >> 1;
  const int ngroup = (l >> 3) * 2 + (xcd & 1);   // [0, 2500)
  const int tid = threadIdx.x;
  const int wv = tid >> 6;
  const int n = ngroup * 4 + wv;
  const int lane = tid & 63;
  const int half = lane >> 5;
  const int lf = lane & 31;
  const int fb = lf * 8;
  const unsigned fbyte = (unsigned)lf * 16u;

  __shared__ uint2 ebuf[4][64];     // {half2(ee,ee) bits, src*512}
  __shared__ uint4 obuf[4][32];     // [wave][d-slot] output staging

  const float tt = tv[m * kN + n];
  const int b = n * kCap;
  const int deg = cnt[n];

  float a_self = sv[m * kN + n] + tt;
  a_self = fmaxf(a_self, kSlope * a_self);
  const float e_self = __expf(a_self);

  const char* hmB = (const char*)(hb + ((size_t)m * kN << 8));  // wave-uniform

  __half2 cacc[4];
  cacc[0] = cacc[1] = cacc[2] = cacc[3] = __float2half2_rn(0.f);
  {
    const __half2 es2 = __float2half2_rn(half ? 0.f : e_self);
    uint4 hx = *(const uint4*)(hmB + (((unsigned)n << 9) + fbyte));
#pragma unroll
    for (int q = 0; q < 4; q++) {
      unsigned w = ((const unsigned*)&hx)[q];
      __half2 hv2 = *reinterpret_cast<const __half2*>(&w);
      cacc[q] = __hfma2(hv2, es2, cacc[q]);
    }
  }
  float denom = (lane == 0) ? e_self : 0.f;

  for (int c0 = 0; c0 < deg; c0 += 64) {
    int j = c0 + lane;
    float ee = 0.f;
    unsigned soff = 0;
    if (j < deg) {
      int src = csr_src[b + j];
      float a = sv[m * kN + src] + tt;
      a = fmaxf(a, kSlope * a);
      ee = __expf(a);
      soff = (unsigned)src << 9;
    }
    denom += ee;
    union { __half2 h2; unsigned u; } ec;
    ec.h2 = __float2half2_rn(ee);
    ebuf[wv][lane] = make_uint2(ec.u, soff);
    const int cl = min(64, deg - c0);
    const uint2* ebase = &ebuf[wv][half];
    for (int j2 = 0; j2 < cl; j2 += 8) {
#pragma unroll
      for (int p = 0; p < 4; p++) {
        uint2 es_ = ebase[j2 + 2 * p];
        __half2 ep2 = *reinterpret_cast<const __half2*>(&es_.x);
        uint4 hx = *(const uint4*)(hmB + (es_.y + fbyte));
#pragma unroll
        for (int q = 0; q < 4; q++) {
          unsigned w = ((const unsigned*)&hx)[q];
          __half2 hv2 = *reinterpret_cast<const __half2*>(&w);
          cacc[q] = __hfma2(hv2, ep2, cacc[q]);
        }
      }
    }
  }
#pragma unroll
  for (int o = 32; o > 0; o >>= 1) denom += __shfl_xor(denom, o);
  const float inv = 1.f / (denom + 1e-16f);

  f32x2 acc2[4];
#pragma unroll
  for (int q = 0; q < 4; q++) {
    float2 f = __half22float2(cacc[q]);
    acc2[q].x = f.x + __shfl_xor(f.x, 32);
    acc2[q].y = f.y + __shfl_xor(f.y, 32);
  }

  if (half == 0) {
    const float* bgp = bg + m * kD + fb;
    float4 b0 = *(const float4*)bgp;
    float4 b1 = *(const float4*)(bgp + 4);
    float4 o0, o1;
    o0.x = fmaxf(acc2[0].x * inv + b0.x, 0.f);
    o0.y = fmaxf(acc2[0].y * inv + b0.y, 0.f);
    o0.z = fmaxf(acc2[1].x * inv + b0.z, 0.f);
    o0.w = fmaxf(acc2[1].y * inv + b0.w, 0.f);
    o1.x = fmaxf(acc2[2].x * inv + b1.x, 0.f);
    o1.y = fmaxf(acc2[2].y * inv + b1.y, 0.f);
    o1.z = fmaxf(acc2[3].x * inv + b1.z, 0.f);
    o1.w = fmaxf(acc2[3].y * inv + b1.w, 0.f);
    obuf[wv][lf] = pack8(o0, o1);
  }
  __syncthreads();
  // coalesced tiled store: 4 threads = 4 consecutive n of one d-slot -> 64B line
  if (tid < 128) {
    const int slot = tid >> 2, nd = tid & 3;
    const int nn = ngroup * 4 + nd;
    *(uint4*)(hrelb + (((size_t)(m * 32 + slot)) * kN + nn) * 8) = obuf[nd][slot];
  }
}

// ---------------- GEMM 2 (MFMA + LDS dbuf, tiled A and B) ----------------------

constexpr int FSTR = 64 * 8 + 8;

__global__ __launch_bounds__(256) void gemm_fused_mfma(const unsigned short* __restrict__ hrelb,
                                                       const unsigned short* __restrict__ Wqt,
                                                       const float* __restrict__ biasp,
                                                       float* __restrict__ out) {
  const int l = blockIdx.x;
  const int xcd = l & 7;
  const int t0 = l >> 3;
  const int c = t0 & 3;
  const int r = (t0 >> 2) * 8 + xcd;
  if (r >= 157) return;
  const int row0 = r * 64;
  const int col0 = c * 64;

  const int tid = threadIdx.x;
  const int wave = tid >> 6, lane = tid & 63;
  const int lidx = lane & 15, lslot = lane >> 4;
  const int wr = wave >> 1, wc = wave & 1;

  __shared__ __align__(16) unsigned short As[2][8 * FSTR];
  __shared__ __align__(16) unsigned short Bs[2][8 * FSTR];

  f32x4 acc[2][2] = {};

  const int arow = min(row0 + (tid & 63), kN - 1);
  const int bcol = col0 + (tid & 63);

#pragma unroll
  for (int ll = 0; ll < 2; ll++) {
    int slot = (tid >> 6) + ll * 4;
    gload_lds16(hrelb + ((size_t)slot * kN + arow) * 8,
                &As[0][slot * FSTR + (tid & 63) * 8]);
    gload_lds16(Wqt + ((size_t)slot << 11) + bcol * 8,
                &Bs[0][slot * FSTR + (tid & 63) * 8]);
  }
  __syncthreads();

  int buf = 0;
  for (int t = 0; t < 16; t++) {
    if (t < 15) {
      const int kb1 = (t + 1) * 8;
#pragma unroll
      for (int ll = 0; ll < 2; ll++) {
        int slot = (tid >> 6) + ll * 4;
        gload_lds16(hrelb + ((size_t)(kb1 + slot) * kN + arow) * 8,
                    &As[buf ^ 1][slot * FSTR + (tid & 63) * 8]);
        gload_lds16(Wqt + ((size_t)(kb1 + slot) << 11) + bcol * 8,
                    &Bs[buf ^ 1][slot * FSTR + (tid & 63) * 8]);
      }
    }
#pragma unroll
    for (int s = 0; s < 2; s++) {
      const int ks = s * 4 + lslot;
      bf16x8 a[2], bfr[2];
#pragma unroll
      for (int i = 0; i < 2; i++)
        a[i] = *(const bf16x8*)&As[buf][ks * FSTR + (wr * 32 + i * 16 + lidx) * 8];
#pragma unroll
      for (int j = 0; j < 2; j++)
        bfr[j] = *(const bf16x8*)&Bs[buf][ks * FSTR + (wc * 32 + j * 16 + lidx) * 8];
#pragma unroll
      for (int i = 0; i < 2; i++)
#pragma unroll
        for (int j = 0; j < 2; j++)
          acc[i][j] = __builtin_amdgcn_mfma_f32_16x16x32_bf16(a[i], bfr[j], acc[i][j], 0, 0, 0);
    }
    __syncthreads();
    buf ^= 1;
  }

  const int slot4 = lane >> 4;
#pragma unroll
  for (int i = 0; i < 2; i++) {
#pragma unroll
    for (int reg = 0; reg < 4; reg++) {
      int grow = row0 + wr * 32 + i * 16 + slot4 * 4 + reg;
      if (grow < kN) {
#pragma unroll
        for (int j = 0; j < 2; j++) {
          int gcol = col0 + wc * 32 + j * 16 + lidx;
          out[(size_t)grow * kP + gcol] = acc[i][j][reg] + biasp[gcol];
        }
      }
    }
  }
}

// ---------------- host launch ----------------

extern "C" void kernel_launch(void* const* d_in, const int* in_sizes, int n_in,
                              void* d_out, int out_size, void* d_ws, size_t ws_size,
                              hipStream_t stream) {
  const float* x = (const float*)d_in[0];
  const int* ei = (const int*)d_in[1];
  const float* Wg = (const float*)d_in[2];
  const float* asrc = (const float*)d_in[3];
  const float* adst = (const float*)d_in[4];
  const float* bg = (const float*)d_in[5];
  const float* Wp = (const float*)d_in[6];
  const float* bp = (const float*)d_in[7];
  const float* cw = (const float*)d_in[8];
  const float* cb = (const float*)d_in[9];
  float* out = (float*)d_out;

  char* ws = (char*)d_ws;
  size_t off = 0;
  auto alloc = [&](size_t bytes) -> void* {
    void* p = ws + off;
    off = (off + bytes + 255) & ~(size_t)255;
    return p;
  };
  unsigned short* hb = (unsigned short*)alloc((size_t)kM * kN * kD * 2);     // fp16 row-major
  unsigned short* hrelb = (unsigned short*)alloc((size_t)kM * kN * kD * 2);  // bf16 k-tiled
  unsigned short* Wgt = (unsigned short*)alloc((size_t)kM * kD * kD * 2);    // bf16 k-tiled
  unsigned short* Wqt = (unsigned short*)alloc((size_t)kP * kM * kD * 2);    // bf16 k-tiled
  float* sv = (float*)alloc((size_t)kM * kN * sizeof(float));
  float* tv = (float*)alloc((size_t)kM * kN * sizeof(float));
  float* biasp = (float*)alloc(kP * sizeof(float));
  int* cnt = (int*)alloc(kN * sizeof(int));
  int* csr_src = (int*)alloc((size_t)kN * kCap * sizeof(int));

  weight_prep_kernel<<<75, 256, 0, stream>>>(Wg, bp, cw, cb, Wgt, biasp, cnt);

  gemm_h_csr_mfma<<<1009, 256, 0, stream>>>(x, Wgt, asrc, adst, ei, cnt, csr_src,
                                            Wp, cw, Wqt, hb, sv, tv);

  gat_aggregate_kernel<<<kN, 256, 0, stream>>>(hb, sv, tv, bg, cnt, csr_src, hrelb);

  gemm_fused_mfma<<<640, 256, 0, stream>>>(hrelb, Wqt, biasp, out);
}